// Round 2
// baseline (735.033 us; speedup 1.0000x reference)
//
#include <hip/hip_runtime.h>
#include <hip/hip_bf16.h>
#include <stdint.h>

// ---------------------------------------------------------------------------
// RandomFeatureAttention: B=4, N=4096, E=1024, H=16, D=64, P_DIM=64, feat=128
// Dtype-agnostic: a detect kernel classifies device storage (fp32 vs bf16),
// a convert pass materializes bf16 copies in ws, all compute runs bf16 MFMA.
// Pipeline:
//   det) storage-dtype probe -> flag in ws
//   cvt) x, Wq, Wk, Wv, Wo -> bf16 ws copies
//   1) K = x@Wk^T+bk -> R1 ; V = x@Wv^T+bv -> R2   (MFMA GEMM 16384x1024x1024)
//   2) kv[bh] = kf^T @ v (fused norm/proj/sincos, reg accum + atomics)
//   3) Q = x@Wq^T+bq -> R2 (V dead)
//   4) o = qf @ kv -> R1 (K dead)
//   5) out = O@Wo^T + bo -> d_out (fp32 or bf16 per flag)
// ---------------------------------------------------------------------------

typedef __bf16 bf16x8 __attribute__((ext_vector_type(8)));
typedef float f32x4 __attribute__((ext_vector_type(4)));

#define AS1 __attribute__((address_space(1)))
#define AS3 __attribute__((address_space(3)))

__device__ __forceinline__ void gl2lds16(const void* g, void* l) {
    __builtin_amdgcn_global_load_lds((const AS1 void*)g, (AS3 void*)l, 16, 0, 0);
}

// ----------------------------- dtype detect --------------------------------
// bf16 storage: first 128 uint16s are bf16(N(0,1)) -> exponents in [117,131]
// for ~all of them. fp32 storage: even uint16s are fp32 mantissa bits ->
// ~uniform "exponents" (~6% in range); odd uint16s look like bf16(x) (~100%).
// => count ~128 (bf16) vs ~68 (fp32). Threshold 100.
__global__ void detect_kernel(const unsigned short* __restrict__ x,
                              int* __restrict__ flag) {
    __shared__ int s;
    const int lane = threadIdx.x;  // 64 threads
    if (lane == 0) s = 0;
    __syncthreads();
    int cnt = 0;
#pragma unroll
    for (int i = 0; i < 2; ++i) {
        const unsigned short u = x[i * 64 + lane];
        const int e = (u >> 7) & 0xFF;
        cnt += (e >= 117 && e <= 131) ? 1 : 0;
    }
    atomicAdd(&s, cnt);
    __syncthreads();
    if (lane == 0) *flag = (s >= 100) ? 1 : 0;  // 1 = bf16 storage
}

// ----------------------------- convert -------------------------------------
// flag==1: bf16 copy. flag==0: fp32 -> bf16. 8 elements/thread.
__global__ __launch_bounds__(256) void cvt_kernel(
    const void* __restrict__ src, __hip_bfloat16* __restrict__ dst,
    int n, const int* __restrict__ flag) {
    const int i = (blockIdx.x * 256 + threadIdx.x) * 8;
    if (i >= n) return;
    if (*flag) {
        *(uint4*)(dst + i) = *(const uint4*)((const __hip_bfloat16*)src + i);
    } else {
        const float* s = (const float*)src + i;
        const float4 a = *(const float4*)s;
        const float4 b = *(const float4*)(s + 4);
        union { uint4 u; __hip_bfloat16 h[8]; } pk;
        pk.h[0] = __float2bfloat16(a.x); pk.h[1] = __float2bfloat16(a.y);
        pk.h[2] = __float2bfloat16(a.z); pk.h[3] = __float2bfloat16(a.w);
        pk.h[4] = __float2bfloat16(b.x); pk.h[5] = __float2bfloat16(b.y);
        pk.h[6] = __float2bfloat16(b.z); pk.h[7] = __float2bfloat16(b.w);
        *(uint4*)(dst + i) = pk.u;
    }
}

// ----------------------------- GEMM ----------------------------------------
// C(M,Nd) = A(M,K) @ W(Nd,K)^T + bias, bf16 in, fp32 accum.
// M=16384, Nd=1024, K=1024. Tile 128x128, BK=64. 256 thr = 4 waves (2x2).
static constexpr int GM = 16384, GN = 1024, GK = 1024;

__global__ __launch_bounds__(256) void gemm_bias_kernel(
    const __hip_bfloat16* __restrict__ A,
    const __hip_bfloat16* __restrict__ W,
    const void* __restrict__ bias_raw,
    void* __restrict__ Cout,
    const int* __restrict__ flag, int last)
{
    __shared__ unsigned short sA[128 * 64];
    __shared__ unsigned short sB[128 * 64];

    const int tid  = threadIdx.x;
    const int lane = tid & 63;
    const int w    = tid >> 6;
    const int wm   = w >> 1, wn = w & 1;
    const int lr   = lane & 15, lk = lane >> 4;
    const int m0   = blockIdx.y * 128;
    const int n0   = blockIdx.x * 128;
    const int fl   = *flag;

    f32x4 acc[4][4];
#pragma unroll
    for (int i = 0; i < 4; ++i)
#pragma unroll
        for (int j = 0; j < 4; ++j)
            acc[i][j] = (f32x4){0.f, 0.f, 0.f, 0.f};

    const __hip_bfloat16* Ab = A + (size_t)m0 * GK;
    const __hip_bfloat16* Wb = W + (size_t)n0 * GK;

    for (int k0 = 0; k0 < GK; k0 += 64) {
#pragma unroll
        for (int j = 0; j < 4; ++j) {
            const int chunk = j * 256 + tid;       // 0..1023
            const int row   = chunk >> 3;
            const int c     = chunk & 7;
            gl2lds16(Ab + (size_t)row * GK + k0 + c * 8,
                     (char*)sA + (j * 256 + w * 64) * 16);
            gl2lds16(Wb + (size_t)row * GK + k0 + c * 8,
                     (char*)sB + (j * 256 + w * 64) * 16);
        }
        __syncthreads();
#pragma unroll
        for (int kk = 0; kk < 64; kk += 32) {
            bf16x8 af[4], bfr[4];
#pragma unroll
            for (int i = 0; i < 4; ++i)
                af[i] = *(const bf16x8*)&sA[(wm * 64 + i * 16 + lr) * 64 + kk + lk * 8];
#pragma unroll
            for (int j = 0; j < 4; ++j)
                bfr[j] = *(const bf16x8*)&sB[(wn * 64 + j * 16 + lr) * 64 + kk + lk * 8];
#pragma unroll
            for (int i = 0; i < 4; ++i)
#pragma unroll
                for (int j = 0; j < 4; ++j)
                    acc[i][j] = __builtin_amdgcn_mfma_f32_16x16x32_bf16(
                        af[i], bfr[j], acc[i][j], 0, 0, 0);
        }
        __syncthreads();
    }

    // epilogue: C/D layout col=lane&15, row=(lane>>4)*4+reg
    const bool f32out = (last != 0) && (fl == 0);
#pragma unroll
    for (int j = 0; j < 4; ++j) {
        const int col = n0 + wn * 64 + j * 16 + lr;
        const float bv = fl ? __bfloat162float(((const __hip_bfloat16*)bias_raw)[col])
                            : ((const float*)bias_raw)[col];
#pragma unroll
        for (int i = 0; i < 4; ++i) {
            const int rbase = m0 + wm * 64 + i * 16 + lk * 4;
#pragma unroll
            for (int r = 0; r < 4; ++r) {
                const size_t idx = (size_t)(rbase + r) * GN + col;
                const float val = acc[i][j][r] + bv;
                if (f32out) ((float*)Cout)[idx] = val;
                else ((__hip_bfloat16*)Cout)[idx] = __float2bfloat16(val);
            }
        }
    }
}

// ----------------------------- kv kernel -----------------------------------
// grid (8 chunks of 512 tokens, 64 bh). kv[bh][e][d] += kf[n][e]*v[n][d].
__global__ __launch_bounds__(256) void kv_kernel(
    const __hip_bfloat16* __restrict__ Km,
    const __hip_bfloat16* __restrict__ Vm,
    const void* __restrict__ Praw,
    float* __restrict__ gKV,
    const int* __restrict__ flag)
{
    __shared__ __hip_bfloat16 sP[64 * 66];    // [e][d]
    __shared__ __hip_bfloat16 sKT[64 * 66];   // [d][n] transposed
    __shared__ __hip_bfloat16 sV[64 * 66];    // [n][d]
    __shared__ __hip_bfloat16 sKF[64 * 134];  // [n][e 0..127]
    __shared__ float sRN[64];

    const int tid  = threadIdx.x;
    const int lane = tid & 63;
    const int w    = tid >> 6;
    const int bh   = blockIdx.y;
    const int b    = bh >> 4, h = bh & 15;
    const int nst  = blockIdx.x * 512;
    const int f    = *flag;

    // load P (64x64), dtype per flag
    for (int i = tid; i < 4096; i += 256) {
        const float pv = f ? __bfloat162float(((const __hip_bfloat16*)Praw)[i])
                           : ((const float*)Praw)[i];
        sP[(i >> 6) * 66 + (i & 63)] = __float2bfloat16(pv);
    }

    const int e0 = 4 * (tid & 31);   // kv-accum feature block
    const int d0 = 8 * (tid >> 5);   // kv-accum d block
    const int pn = 4 * (tid & 15);   // projection n block
    const int pe = 4 * (tid >> 4);   // projection e block

    float acc[4][8];
#pragma unroll
    for (int i = 0; i < 4; ++i)
#pragma unroll
        for (int j = 0; j < 8; ++j) acc[i][j] = 0.f;

    for (int s = 0; s < 8; ++s) {
        const int n0 = nst + s * 64;
        __syncthreads();  // protect LDS reuse (covers P load on s==0)
        for (int i = tid; i < 512; i += 256) {
            const int r = i >> 3, c = i & 7;
            const size_t base = (size_t)(b * 4096 + n0 + r) * 1024 + h * 64 + c * 8;
            uint4 ku = *(const uint4*)(Km + base);
            uint4 vu = *(const uint4*)(Vm + base);
            const __hip_bfloat16* kh = (const __hip_bfloat16*)&ku;
#pragma unroll
            for (int jj = 0; jj < 8; ++jj) sKT[(8 * c + jj) * 66 + r] = kh[jj];
            uint32_t* vdst = (uint32_t*)&sV[r * 66 + c * 8];
            const uint32_t* vsrc = (const uint32_t*)&vu;
            vdst[0] = vsrc[0]; vdst[1] = vsrc[1]; vdst[2] = vsrc[2]; vdst[3] = vsrc[3];
        }
        __syncthreads();
        {
            float ssum = 0.f;
#pragma unroll 8
            for (int d = 0; d < 64; ++d) {
                const float kd = __bfloat162float(sKT[d * 66 + lane]);
                ssum += kd * kd;
            }
            if (w == 0) sRN[lane] = 2.0f / (sqrtf(ssum) + 1e-4f);  // scale=H^0.25=2
        }
        __syncthreads();
        {
            float kp[4][4];
#pragma unroll
            for (int i = 0; i < 4; ++i)
#pragma unroll
                for (int jj = 0; jj < 4; ++jj) kp[i][jj] = 0.f;
            for (int d = 0; d < 64; ++d) {
                float kr[4], pr[4];
#pragma unroll
                for (int i = 0; i < 4; ++i) kr[i] = __bfloat162float(sKT[d * 66 + pn + i]);
#pragma unroll
                for (int jj = 0; jj < 4; ++jj) pr[jj] = __bfloat162float(sP[(pe + jj) * 66 + d]);
#pragma unroll
                for (int i = 0; i < 4; ++i)
#pragma unroll
                    for (int jj = 0; jj < 4; ++jj) kp[i][jj] += kr[i] * pr[jj];
            }
#pragma unroll
            for (int i = 0; i < 4; ++i) {
                const float rn = sRN[pn + i];
#pragma unroll
                for (int jj = 0; jj < 4; ++jj) {
                    const float val = kp[i][jj] * rn;
                    float sv, cv;
                    __sincosf(val, &sv, &cv);
                    sKF[(pn + i) * 134 + pe + jj]      = __float2bfloat16(sv * 0.125f);
                    sKF[(pn + i) * 134 + 64 + pe + jj] = __float2bfloat16(cv * 0.125f);
                }
            }
        }
        __syncthreads();
        for (int n = 0; n < 64; ++n) {
            float ff[4], vv[8];
#pragma unroll
            for (int i = 0; i < 4; ++i) ff[i] = __bfloat162float(sKF[n * 134 + e0 + i]);
#pragma unroll
            for (int jj = 0; jj < 8; ++jj) vv[jj] = __bfloat162float(sV[n * 66 + d0 + jj]);
#pragma unroll
            for (int i = 0; i < 4; ++i)
#pragma unroll
                for (int jj = 0; jj < 8; ++jj) acc[i][jj] += ff[i] * vv[jj];
        }
    }

    float* out = gKV + (size_t)bh * 128 * 64;
#pragma unroll
    for (int i = 0; i < 4; ++i)
#pragma unroll
        for (int jj = 0; jj < 8; ++jj)
            atomicAdd(out + (e0 + i) * 64 + d0 + jj, acc[i][jj]);
}

// ----------------------------- o kernel ------------------------------------
// o[b,n,h*64+d] = sum_e qf[n,e] * kv[e,d]
__global__ __launch_bounds__(256) void o_kernel(
    const __hip_bfloat16* __restrict__ Qm,
    const void* __restrict__ Praw,
    const float* __restrict__ gKV,
    __hip_bfloat16* __restrict__ O,
    const int* __restrict__ flag)
{
    __shared__ __hip_bfloat16 sP[64 * 66];
    __shared__ __hip_bfloat16 sQT[64 * 66];   // [d][n]
    __shared__ __hip_bfloat16 sQF[64 * 134];  // [n][e]
    __shared__ __hip_bfloat16 sKV[128 * 68];  // [e][d]
    __shared__ float sRN[64];

    const int tid  = threadIdx.x;
    const int lane = tid & 63;
    const int w    = tid >> 6;
    const int bh   = blockIdx.y;
    const int b    = bh >> 4, h = bh & 15;
    const int nst  = blockIdx.x * 512;
    const int f    = *flag;
    const int pn   = 4 * (tid & 15);  // n block (proj + o)
    const int pe   = 4 * (tid >> 4);  // e block (proj) / d block (o)

    for (int i = tid; i < 4096; i += 256) {
        const float pv = f ? __bfloat162float(((const __hip_bfloat16*)Praw)[i])
                           : ((const float*)Praw)[i];
        sP[(i >> 6) * 66 + (i & 63)] = __float2bfloat16(pv);
    }
    const float* kvsrc = gKV + (size_t)bh * 8192;
    for (int i = tid; i < 8192; i += 256) {
        const int e = i >> 6, d = i & 63;
        sKV[e * 68 + d] = __float2bfloat16(kvsrc[i]);
    }

    for (int s = 0; s < 8; ++s) {
        const int n0 = nst + s * 64;
        __syncthreads();  // covers sP/sKV loads on s==0, LDS reuse otherwise
        for (int i = tid; i < 512; i += 256) {
            const int r = i >> 3, c = i & 7;
            uint4 qu = *(const uint4*)(Qm + (size_t)(b * 4096 + n0 + r) * 1024 + h * 64 + c * 8);
            const __hip_bfloat16* qh = (const __hip_bfloat16*)&qu;
#pragma unroll
            for (int jj = 0; jj < 8; ++jj) sQT[(8 * c + jj) * 66 + r] = qh[jj];
        }
        __syncthreads();
        {
            float ssum = 0.f;
#pragma unroll 8
            for (int d = 0; d < 64; ++d) {
                const float qd = __bfloat162float(sQT[d * 66 + lane]);
                ssum += qd * qd;
            }
            if (w == 0) sRN[lane] = 2.0f / (sqrtf(ssum) + 1e-4f);
        }
        __syncthreads();
        {
            float qp[4][4];
#pragma unroll
            for (int i = 0; i < 4; ++i)
#pragma unroll
                for (int jj = 0; jj < 4; ++jj) qp[i][jj] = 0.f;
            for (int d = 0; d < 64; ++d) {
                float qr[4], pr[4];
#pragma unroll
                for (int i = 0; i < 4; ++i) qr[i] = __bfloat162float(sQT[d * 66 + pn + i]);
#pragma unroll
                for (int jj = 0; jj < 4; ++jj) pr[jj] = __bfloat162float(sP[(pe + jj) * 66 + d]);
#pragma unroll
                for (int i = 0; i < 4; ++i)
#pragma unroll
                    for (int jj = 0; jj < 4; ++jj) qp[i][jj] += qr[i] * pr[jj];
            }
#pragma unroll
            for (int i = 0; i < 4; ++i) {
                const float rn = sRN[pn + i];
#pragma unroll
                for (int jj = 0; jj < 4; ++jj) {
                    const float val = qp[i][jj] * rn;
                    float sv, cv;
                    __sincosf(val, &sv, &cv);
                    sQF[(pn + i) * 134 + pe + jj]      = __float2bfloat16(sv * 0.125f);
                    sQF[(pn + i) * 134 + 64 + pe + jj] = __float2bfloat16(cv * 0.125f);
                }
            }
        }
        __syncthreads();
        float o[4][4];
#pragma unroll
        for (int i = 0; i < 4; ++i)
#pragma unroll
            for (int jj = 0; jj < 4; ++jj) o[i][jj] = 0.f;
        for (int e = 0; e < 128; ++e) {
            float q[4], kvr[4];
#pragma unroll
            for (int i = 0; i < 4; ++i) q[i] = __bfloat162float(sQF[(pn + i) * 134 + e]);
#pragma unroll
            for (int jj = 0; jj < 4; ++jj) kvr[jj] = __bfloat162float(sKV[e * 68 + pe + jj]);
#pragma unroll
            for (int i = 0; i < 4; ++i)
#pragma unroll
                for (int jj = 0; jj < 4; ++jj) o[i][jj] += q[i] * kvr[jj];
        }
#pragma unroll
        for (int i = 0; i < 4; ++i) {
            union { uint2 u; __hip_bfloat16 hh[4]; } pk;
#pragma unroll
            for (int jj = 0; jj < 4; ++jj) pk.hh[jj] = __float2bfloat16(o[i][jj]);
            *(uint2*)(O + (size_t)(b * 4096 + n0 + pn + i) * 1024 + h * 64 + pe) = pk.u;
        }
    }
}

// ----------------------------- launcher ------------------------------------
extern "C" void kernel_launch(void* const* d_in, const int* in_sizes, int n_in,
                              void* d_out, int out_size, void* d_ws, size_t ws_size,
                              hipStream_t stream)
{
    (void)in_sizes; (void)n_in; (void)out_size; (void)ws_size;
    const void* x  = d_in[0];
    const void* Wq = d_in[1];
    const void* bq = d_in[2];
    const void* Wk = d_in[3];
    const void* bk = d_in[4];
    const void* Wv = d_in[5];
    const void* bv = d_in[6];
    const void* Wo = d_in[7];
    const void* bo = d_in[8];
    const void* P  = d_in[9];

    constexpr size_t XE = (size_t)GM * GN;   // 16777216
    constexpr size_t WE = (size_t)GN * GK;   // 1048576
    __hip_bfloat16* xb  = (__hip_bfloat16*)d_ws;
    __hip_bfloat16* wqb = xb + XE;
    __hip_bfloat16* wkb = wqb + WE;
    __hip_bfloat16* wvb = wkb + WE;
    __hip_bfloat16* wob = wvb + WE;
    __hip_bfloat16* R1  = wob + WE;          // K, later O
    __hip_bfloat16* R2  = R1 + XE;           // V, later Q
    float* gKV = (float*)(R2 + XE);          // 64*128*64 fp32
    int* flag  = (int*)(gKV + (size_t)64 * 128 * 64);

    dim3 blk(256);
    hipLaunchKernelGGL(detect_kernel, dim3(1), dim3(64), 0, stream,
                       (const unsigned short*)x, flag);
    hipMemsetAsync(gKV, 0, (size_t)64 * 128 * 64 * sizeof(float), stream);

    hipLaunchKernelGGL(cvt_kernel, dim3(8192), blk, 0, stream, x,  xb,  (int)XE, flag);
    hipLaunchKernelGGL(cvt_kernel, dim3(512),  blk, 0, stream, Wq, wqb, (int)WE, flag);
    hipLaunchKernelGGL(cvt_kernel, dim3(512),  blk, 0, stream, Wk, wkb, (int)WE, flag);
    hipLaunchKernelGGL(cvt_kernel, dim3(512),  blk, 0, stream, Wv, wvb, (int)WE, flag);
    hipLaunchKernelGGL(cvt_kernel, dim3(512),  blk, 0, stream, Wo, wob, (int)WE, flag);

    dim3 gemm_grid(GN / 128, GM / 128);
    hipLaunchKernelGGL(gemm_bias_kernel, gemm_grid, blk, 0, stream, xb, wkb, bk, R1, flag, 0); // K
    hipLaunchKernelGGL(gemm_bias_kernel, gemm_grid, blk, 0, stream, xb, wvb, bv, R2, flag, 0); // V
    hipLaunchKernelGGL(kv_kernel, dim3(8, 64), blk, 0, stream, R1, R2, P, gKV, flag);
    hipLaunchKernelGGL(gemm_bias_kernel, gemm_grid, blk, 0, stream, xb, wqb, bq, R2, flag, 0); // Q (V dead)
    hipLaunchKernelGGL(o_kernel, dim3(8, 64), blk, 0, stream, R2, P, gKV, R1, flag);           // O (K dead)
    hipLaunchKernelGGL(gemm_bias_kernel, gemm_grid, blk, 0, stream, R1, wob, bo, d_out, flag, 1);
}

// Round 3
// 455.879 us; speedup vs baseline: 1.6123x; 1.6123x over previous
//
#include <hip/hip_runtime.h>
#include <hip/hip_bf16.h>
#include <stdint.h>

// ---------------------------------------------------------------------------
// RandomFeatureAttention: B=4, N=4096, E=1024, H=16, D=64, P_DIM=64, feat=128
// Round 3: middle kernels (kv, o) rewritten around MFMA.
//   det) storage-dtype probe -> flag in ws
//   cvt) x, Wq, Wk, Wv, Wo -> bf16 ws copies
//   1) K = x@Wk^T+bk -> R1 ; V = x@Wv^T+bv -> R2   (MFMA GEMM 16384x1024x1024)
//   2) kv[bh] = kf^T @ v   (MFMA: proj -> sincos -> outer-accumulate)
//   3) Q = x@Wq^T+bq -> R2 (V dead)
//   4) o = qf @ kv -> R1   (K dead; MFMA)
//   5) out = O@Wo^T + bo -> d_out (fp32 or bf16 per flag)
// ---------------------------------------------------------------------------

typedef __bf16 bf16x8 __attribute__((ext_vector_type(8)));
typedef float f32x4 __attribute__((ext_vector_type(4)));

#define AS1 __attribute__((address_space(1)))
#define AS3 __attribute__((address_space(3)))

__device__ __forceinline__ void gl2lds16(const void* g, void* l) {
    __builtin_amdgcn_global_load_lds((const AS1 void*)g, (AS3 void*)l, 16, 0, 0);
}

// ----------------------------- dtype detect --------------------------------
__global__ void detect_kernel(const unsigned short* __restrict__ x,
                              int* __restrict__ flag) {
    __shared__ int s;
    const int lane = threadIdx.x;  // 64 threads
    if (lane == 0) s = 0;
    __syncthreads();
    int cnt = 0;
#pragma unroll
    for (int i = 0; i < 2; ++i) {
        const unsigned short u = x[i * 64 + lane];
        const int e = (u >> 7) & 0xFF;
        cnt += (e >= 117 && e <= 131) ? 1 : 0;
    }
    atomicAdd(&s, cnt);
    __syncthreads();
    if (lane == 0) *flag = (s >= 100) ? 1 : 0;  // 1 = bf16 storage
}

// ----------------------------- convert -------------------------------------
__global__ __launch_bounds__(256) void cvt_kernel(
    const void* __restrict__ src, __hip_bfloat16* __restrict__ dst,
    int n, const int* __restrict__ flag) {
    const int i = (blockIdx.x * 256 + threadIdx.x) * 8;
    if (i >= n) return;
    if (*flag) {
        *(uint4*)(dst + i) = *(const uint4*)((const __hip_bfloat16*)src + i);
    } else {
        const float* s = (const float*)src + i;
        const float4 a = *(const float4*)s;
        const float4 b = *(const float4*)(s + 4);
        union { uint4 u; __hip_bfloat16 h[8]; } pk;
        pk.h[0] = __float2bfloat16(a.x); pk.h[1] = __float2bfloat16(a.y);
        pk.h[2] = __float2bfloat16(a.z); pk.h[3] = __float2bfloat16(a.w);
        pk.h[4] = __float2bfloat16(b.x); pk.h[5] = __float2bfloat16(b.y);
        pk.h[6] = __float2bfloat16(b.z); pk.h[7] = __float2bfloat16(b.w);
        *(uint4*)(dst + i) = pk.u;
    }
}

// ----------------------------- GEMM ----------------------------------------
static constexpr int GM = 16384, GN = 1024, GK = 1024;

__global__ __launch_bounds__(256) void gemm_bias_kernel(
    const __hip_bfloat16* __restrict__ A,
    const __hip_bfloat16* __restrict__ W,
    const void* __restrict__ bias_raw,
    void* __restrict__ Cout,
    const int* __restrict__ flag, int last)
{
    __shared__ unsigned short sA[128 * 64];
    __shared__ unsigned short sB[128 * 64];

    const int tid  = threadIdx.x;
    const int lane = tid & 63;
    const int w    = tid >> 6;
    const int wm   = w >> 1, wn = w & 1;
    const int lr   = lane & 15, lk = lane >> 4;
    const int m0   = blockIdx.y * 128;
    const int n0   = blockIdx.x * 128;
    const int fl   = *flag;

    f32x4 acc[4][4];
#pragma unroll
    for (int i = 0; i < 4; ++i)
#pragma unroll
        for (int j = 0; j < 4; ++j)
            acc[i][j] = (f32x4){0.f, 0.f, 0.f, 0.f};

    const __hip_bfloat16* Ab = A + (size_t)m0 * GK;
    const __hip_bfloat16* Wb = W + (size_t)n0 * GK;

    for (int k0 = 0; k0 < GK; k0 += 64) {
#pragma unroll
        for (int j = 0; j < 4; ++j) {
            const int chunk = j * 256 + tid;
            const int row   = chunk >> 3;
            const int c     = chunk & 7;
            gl2lds16(Ab + (size_t)row * GK + k0 + c * 8,
                     (char*)sA + (j * 256 + w * 64) * 16);
            gl2lds16(Wb + (size_t)row * GK + k0 + c * 8,
                     (char*)sB + (j * 256 + w * 64) * 16);
        }
        __syncthreads();
#pragma unroll
        for (int kk = 0; kk < 64; kk += 32) {
            bf16x8 af[4], bfr[4];
#pragma unroll
            for (int i = 0; i < 4; ++i)
                af[i] = *(const bf16x8*)&sA[(wm * 64 + i * 16 + lr) * 64 + kk + lk * 8];
#pragma unroll
            for (int j = 0; j < 4; ++j)
                bfr[j] = *(const bf16x8*)&sB[(wn * 64 + j * 16 + lr) * 64 + kk + lk * 8];
#pragma unroll
            for (int i = 0; i < 4; ++i)
#pragma unroll
                for (int j = 0; j < 4; ++j)
                    acc[i][j] = __builtin_amdgcn_mfma_f32_16x16x32_bf16(
                        af[i], bfr[j], acc[i][j], 0, 0, 0);
        }
        __syncthreads();
    }

    const bool f32out = (last != 0) && (fl == 0);
#pragma unroll
    for (int j = 0; j < 4; ++j) {
        const int col = n0 + wn * 64 + j * 16 + lr;
        const float bv = fl ? __bfloat162float(((const __hip_bfloat16*)bias_raw)[col])
                            : ((const float*)bias_raw)[col];
#pragma unroll
        for (int i = 0; i < 4; ++i) {
            const int rbase = m0 + wm * 64 + i * 16 + lk * 4;
#pragma unroll
            for (int r = 0; r < 4; ++r) {
                const size_t idx = (size_t)(rbase + r) * GN + col;
                const float val = acc[i][j][r] + bv;
                if (f32out) ((float*)Cout)[idx] = val;
                else ((__hip_bfloat16*)Cout)[idx] = __float2bfloat16(val);
            }
        }
    }
}

// ----------------------------- shared helpers -------------------------------
// Load P (64x64) into LDS [e][d], stride 72 (16B-aligned rows, 2-way banks).
__device__ __forceinline__ void load_P(const void* Praw, int f,
                                       __hip_bfloat16* sP, int tid) {
    const int e = tid >> 2, q = tid & 3;
    union { uint4 u[2]; __hip_bfloat16 h[16]; } pk;
    if (f) {
        pk.u[0] = *(const uint4*)((const __hip_bfloat16*)Praw + e * 64 + q * 16);
        pk.u[1] = *(const uint4*)((const __hip_bfloat16*)Praw + e * 64 + q * 16 + 8);
    } else {
        const float* ps = (const float*)Praw + e * 64 + q * 16;
#pragma unroll
        for (int j = 0; j < 16; ++j) pk.h[j] = __float2bfloat16(ps[j]);
    }
    *(uint4*)&sP[e * 72 + q * 16]     = pk.u[0];
    *(uint4*)&sP[e * 72 + q * 16 + 8] = pk.u[1];
}

// ----------------------------- kv kernel -----------------------------------
// grid (8, 64): 512-token chunk per block. kv[bh][e][d] += kf[n][e]*v[n][d].
__global__ __launch_bounds__(256) void kv_kernel(
    const __hip_bfloat16* __restrict__ Km,
    const __hip_bfloat16* __restrict__ Vm,
    const void* __restrict__ Praw,
    float* __restrict__ gKV,
    const int* __restrict__ flag)
{
    __shared__ __hip_bfloat16 sK[64 * 72];     // [n][d]
    __shared__ __hip_bfloat16 sVT[64 * 72];    // [d][n]
    __shared__ __hip_bfloat16 sP[64 * 72];     // [e][d]
    __shared__ __hip_bfloat16 sKFT[128 * 72];  // [e][n]
    __shared__ float sRN[64];

    const int tid  = threadIdx.x;
    const int lane = tid & 63;
    const int w    = tid >> 6;
    const int lr   = lane & 15, lk = lane >> 4;
    const int bh   = blockIdx.y;
    const int b    = bh >> 4, h = bh & 15;
    const int nst  = blockIdx.x * 512;
    const int f    = *flag;

    load_P(Praw, f, sP, tid);

    f32x4 acck[2][4];
#pragma unroll
    for (int i = 0; i < 2; ++i)
#pragma unroll
        for (int j = 0; j < 4; ++j)
            acck[i][j] = (f32x4){0.f, 0.f, 0.f, 0.f};

    for (int s = 0; s < 8; ++s) {
        const int gn0 = nst + s * 64;
        __syncthreads();  // protect LDS overwrite (covers P load on s==0)
        // stage K [n][d] and V^T [d][n]
        {
            const int n = tid >> 2, q = tid & 3;
            const size_t base = ((size_t)(b * 4096 + gn0 + n)) * 1024 + h * 64 + q * 16;
            uint4 k0 = *(const uint4*)(Km + base);
            uint4 k1 = *(const uint4*)(Km + base + 8);
            *(uint4*)&sK[n * 72 + q * 16]     = k0;
            *(uint4*)&sK[n * 72 + q * 16 + 8] = k1;
            union { uint4 u[2]; __hip_bfloat16 h[16]; } vv;
            vv.u[0] = *(const uint4*)(Vm + base);
            vv.u[1] = *(const uint4*)(Vm + base + 8);
#pragma unroll
            for (int j = 0; j < 16; ++j) sVT[(q * 16 + j) * 72 + n] = vv.h[j];
        }
        __syncthreads();
        // per-token 1/(norm+eps) * H^0.25 : 4 lanes per token
        {
            const int tl = lane >> 2, q2 = lane & 3;
            const int token = w * 16 + tl;
            union { bf16x8 v; __hip_bfloat16 h[8]; } a0, a1;
            a0.v = *(const bf16x8*)&sK[token * 72 + q2 * 16];
            a1.v = *(const bf16x8*)&sK[token * 72 + q2 * 16 + 8];
            float ss = 0.f;
#pragma unroll
            for (int j = 0; j < 8; ++j) {
                float x0 = __bfloat162float(a0.h[j]); ss += x0 * x0;
                float x1 = __bfloat162float(a1.h[j]); ss += x1 * x1;
            }
            ss += __shfl_xor(ss, 1, 64);
            ss += __shfl_xor(ss, 2, 64);
            if (q2 == 0) sRN[token] = 2.0f / (sqrtf(ss) + 1e-4f);
        }
        __syncthreads();
        // projection MFMA (wave w -> tokens w*16..+15) + sincos -> sKFT
        {
            bf16x8 afr0 = *(const bf16x8*)&sK[(w * 16 + lr) * 72 + lk * 8];
            bf16x8 afr1 = *(const bf16x8*)&sK[(w * 16 + lr) * 72 + 32 + lk * 8];
            float rn[4];
#pragma unroll
            for (int r = 0; r < 4; ++r) rn[r] = sRN[w * 16 + lk * 4 + r];
#pragma unroll
            for (int eb = 0; eb < 4; ++eb) {
                f32x4 pa = (f32x4){0.f, 0.f, 0.f, 0.f};
                bf16x8 b0 = *(const bf16x8*)&sP[(eb * 16 + lr) * 72 + lk * 8];
                bf16x8 b1 = *(const bf16x8*)&sP[(eb * 16 + lr) * 72 + 32 + lk * 8];
                pa = __builtin_amdgcn_mfma_f32_16x16x32_bf16(afr0, b0, pa, 0, 0, 0);
                pa = __builtin_amdgcn_mfma_f32_16x16x32_bf16(afr1, b1, pa, 0, 0, 0);
                const int col = eb * 16 + lr;
#pragma unroll
                for (int r = 0; r < 4; ++r) {
                    const int row = w * 16 + lk * 4 + r;
                    float sv, cv;
                    __sincosf(pa[r] * rn[r], &sv, &cv);
                    sKFT[col * 72 + row]        = __float2bfloat16(sv * 0.125f);
                    sKFT[(col + 64) * 72 + row] = __float2bfloat16(cv * 0.125f);
                }
            }
        }
        __syncthreads();
        // kv MFMA: M=128(e) x N=64(d) x K=64(n); wave w -> e-blocks {w, w+4}
#pragma unroll
        for (int ks = 0; ks < 2; ++ks) {
            bf16x8 a2[2], b2[4];
            a2[0] = *(const bf16x8*)&sKFT[(w * 16 + lr) * 72 + ks * 32 + lk * 8];
            a2[1] = *(const bf16x8*)&sKFT[((w + 4) * 16 + lr) * 72 + ks * 32 + lk * 8];
#pragma unroll
            for (int db = 0; db < 4; ++db)
                b2[db] = *(const bf16x8*)&sVT[(db * 16 + lr) * 72 + ks * 32 + lk * 8];
#pragma unroll
            for (int i = 0; i < 2; ++i)
#pragma unroll
                for (int db = 0; db < 4; ++db)
                    acck[i][db] = __builtin_amdgcn_mfma_f32_16x16x32_bf16(
                        a2[i], b2[db], acck[i][db], 0, 0, 0);
        }
    }

    float* out = gKV + (size_t)bh * 8192;
#pragma unroll
    for (int i = 0; i < 2; ++i)
#pragma unroll
        for (int db = 0; db < 4; ++db)
#pragma unroll
            for (int r = 0; r < 4; ++r) {
                const int e = (w + 4 * i) * 16 + lk * 4 + r;
                const int d = db * 16 + lr;
                atomicAdd(out + e * 64 + d, acck[i][db][r]);
            }
}

// ----------------------------- o kernel ------------------------------------
// grid (16, 64): 256-token chunk per block. o = qf @ kv.
__global__ __launch_bounds__(256) void o_kernel(
    const __hip_bfloat16* __restrict__ Qm,
    const void* __restrict__ Praw,
    const float* __restrict__ gKV,
    __hip_bfloat16* __restrict__ O,
    const int* __restrict__ flag)
{
    __shared__ __hip_bfloat16 sQ[64 * 72];     // [n][d], reused as o-tile [n][d]
    __shared__ __hip_bfloat16 sP[64 * 72];     // [e][d]
    __shared__ __hip_bfloat16 sQF[64 * 136];   // [n][e 0..127]
    __shared__ __hip_bfloat16 sKVT[64 * 136];  // [d][e]
    __shared__ float sRN[64];

    const int tid  = threadIdx.x;
    const int lane = tid & 63;
    const int w    = tid >> 6;
    const int lr   = lane & 15, lk = lane >> 4;
    const int bh   = blockIdx.y;
    const int b    = bh >> 4, h = bh & 15;
    const int nst  = blockIdx.x * 256;
    const int f    = *flag;

    load_P(Praw, f, sP, tid);
    {
        const float* kvsrc = gKV + (size_t)bh * 8192;
        for (int t = tid; t < 8192; t += 256) {
            const int e = t >> 6, d = t & 63;
            sKVT[d * 136 + e] = __float2bfloat16(kvsrc[t]);
        }
    }

    for (int s = 0; s < 4; ++s) {
        const int gn0 = nst + s * 64;
        __syncthreads();  // covers sP/sKVT loads on s==0; LDS reuse otherwise
        {
            const int n = tid >> 2, q = tid & 3;
            const size_t base = ((size_t)(b * 4096 + gn0 + n)) * 1024 + h * 64 + q * 16;
            uint4 q0 = *(const uint4*)(Qm + base);
            uint4 q1 = *(const uint4*)(Qm + base + 8);
            *(uint4*)&sQ[n * 72 + q * 16]     = q0;
            *(uint4*)&sQ[n * 72 + q * 16 + 8] = q1;
        }
        __syncthreads();
        {
            const int tl = lane >> 2, q2 = lane & 3;
            const int token = w * 16 + tl;
            union { bf16x8 v; __hip_bfloat16 h[8]; } a0, a1;
            a0.v = *(const bf16x8*)&sQ[token * 72 + q2 * 16];
            a1.v = *(const bf16x8*)&sQ[token * 72 + q2 * 16 + 8];
            float ss = 0.f;
#pragma unroll
            for (int j = 0; j < 8; ++j) {
                float x0 = __bfloat162float(a0.h[j]); ss += x0 * x0;
                float x1 = __bfloat162float(a1.h[j]); ss += x1 * x1;
            }
            ss += __shfl_xor(ss, 1, 64);
            ss += __shfl_xor(ss, 2, 64);
            if (q2 == 0) sRN[token] = 2.0f / (sqrtf(ss) + 1e-4f);
        }
        __syncthreads();
        {
            bf16x8 afr0 = *(const bf16x8*)&sQ[(w * 16 + lr) * 72 + lk * 8];
            bf16x8 afr1 = *(const bf16x8*)&sQ[(w * 16 + lr) * 72 + 32 + lk * 8];
            float rn[4];
#pragma unroll
            for (int r = 0; r < 4; ++r) rn[r] = sRN[w * 16 + lk * 4 + r];
#pragma unroll
            for (int eb = 0; eb < 4; ++eb) {
                f32x4 pa = (f32x4){0.f, 0.f, 0.f, 0.f};
                bf16x8 b0 = *(const bf16x8*)&sP[(eb * 16 + lr) * 72 + lk * 8];
                bf16x8 b1 = *(const bf16x8*)&sP[(eb * 16 + lr) * 72 + 32 + lk * 8];
                pa = __builtin_amdgcn_mfma_f32_16x16x32_bf16(afr0, b0, pa, 0, 0, 0);
                pa = __builtin_amdgcn_mfma_f32_16x16x32_bf16(afr1, b1, pa, 0, 0, 0);
                const int col = eb * 16 + lr;
#pragma unroll
                for (int r = 0; r < 4; ++r) {
                    const int row = w * 16 + lk * 4 + r;
                    float sv, cv;
                    __sincosf(pa[r] * rn[r], &sv, &cv);
                    sQF[row * 136 + col]      = __float2bfloat16(sv * 0.125f);
                    sQF[row * 136 + 64 + col] = __float2bfloat16(cv * 0.125f);
                }
            }
        }
        __syncthreads();
        // o MFMA: M=64(n) x N=64(d) x K=128(e); wave w -> token block w
        f32x4 oacc[4];
#pragma unroll
        for (int nb = 0; nb < 4; ++nb) oacc[nb] = (f32x4){0.f, 0.f, 0.f, 0.f};
#pragma unroll
        for (int ks = 0; ks < 4; ++ks) {
            bf16x8 aa = *(const bf16x8*)&sQF[(w * 16 + lr) * 136 + ks * 32 + lk * 8];
#pragma unroll
            for (int nb = 0; nb < 4; ++nb) {
                bf16x8 bb = *(const bf16x8*)&sKVT[(nb * 16 + lr) * 136 + ks * 32 + lk * 8];
                oacc[nb] = __builtin_amdgcn_mfma_f32_16x16x32_bf16(aa, bb, oacc[nb], 0, 0, 0);
            }
        }
        // pack through LDS (reuse sQ) for vectorized global stores
#pragma unroll
        for (int nb = 0; nb < 4; ++nb)
#pragma unroll
            for (int r = 0; r < 4; ++r)
                sQ[(w * 16 + lk * 4 + r) * 72 + nb * 16 + lr] =
                    __float2bfloat16(oacc[nb][r]);
        __syncthreads();
        {
            const int n = tid >> 2, q = tid & 3;
            uint4 o0 = *(uint4*)&sQ[n * 72 + q * 16];
            uint4 o1 = *(uint4*)&sQ[n * 72 + q * 16 + 8];
            const size_t obase = ((size_t)(b * 4096 + gn0 + n)) * 1024 + h * 64 + q * 16;
            *(uint4*)(O + obase)     = o0;
            *(uint4*)(O + obase + 8) = o1;
        }
    }
}

// ----------------------------- launcher ------------------------------------
extern "C" void kernel_launch(void* const* d_in, const int* in_sizes, int n_in,
                              void* d_out, int out_size, void* d_ws, size_t ws_size,
                              hipStream_t stream)
{
    (void)in_sizes; (void)n_in; (void)out_size; (void)ws_size;
    const void* x  = d_in[0];
    const void* Wq = d_in[1];
    const void* bq = d_in[2];
    const void* Wk = d_in[3];
    const void* bk = d_in[4];
    const void* Wv = d_in[5];
    const void* bv = d_in[6];
    const void* Wo = d_in[7];
    const void* bo = d_in[8];
    const void* P  = d_in[9];

    constexpr size_t XE = (size_t)GM * GN;   // 16777216
    constexpr size_t WE = (size_t)GN * GK;   // 1048576
    __hip_bfloat16* xb  = (__hip_bfloat16*)d_ws;
    __hip_bfloat16* wqb = xb + XE;
    __hip_bfloat16* wkb = wqb + WE;
    __hip_bfloat16* wvb = wkb + WE;
    __hip_bfloat16* wob = wvb + WE;
    __hip_bfloat16* R1  = wob + WE;          // K, later O
    __hip_bfloat16* R2  = R1 + XE;           // V, later Q
    float* gKV = (float*)(R2 + XE);          // 64*128*64 fp32
    int* flag  = (int*)(gKV + (size_t)64 * 128 * 64);

    dim3 blk(256);
    hipLaunchKernelGGL(detect_kernel, dim3(1), dim3(64), 0, stream,
                       (const unsigned short*)x, flag);
    hipMemsetAsync(gKV, 0, (size_t)64 * 128 * 64 * sizeof(float), stream);

    hipLaunchKernelGGL(cvt_kernel, dim3(8192), blk, 0, stream, x,  xb,  (int)XE, flag);
    hipLaunchKernelGGL(cvt_kernel, dim3(512),  blk, 0, stream, Wq, wqb, (int)WE, flag);
    hipLaunchKernelGGL(cvt_kernel, dim3(512),  blk, 0, stream, Wk, wkb, (int)WE, flag);
    hipLaunchKernelGGL(cvt_kernel, dim3(512),  blk, 0, stream, Wv, wvb, (int)WE, flag);
    hipLaunchKernelGGL(cvt_kernel, dim3(512),  blk, 0, stream, Wo, wob, (int)WE, flag);

    dim3 gemm_grid(GN / 128, GM / 128);
    hipLaunchKernelGGL(gemm_bias_kernel, gemm_grid, blk, 0, stream, xb, wkb, bk, R1, flag, 0); // K
    hipLaunchKernelGGL(gemm_bias_kernel, gemm_grid, blk, 0, stream, xb, wvb, bv, R2, flag, 0); // V
    hipLaunchKernelGGL(kv_kernel, dim3(8, 64), blk, 0, stream, R1, R2, P, gKV, flag);
    hipLaunchKernelGGL(gemm_bias_kernel, gemm_grid, blk, 0, stream, xb, wqb, bq, R2, flag, 0); // Q (V dead)
    hipLaunchKernelGGL(o_kernel, dim3(16, 64), blk, 0, stream, R2, P, gKV, R1, flag);          // O (K dead)
    hipLaunchKernelGGL(gemm_bias_kernel, gemm_grid, blk, 0, stream, R1, wob, bo, d_out, flag, 1);
}

// Round 4
// 426.404 us; speedup vs baseline: 1.7238x; 1.0691x over previous
//
#include <hip/hip_runtime.h>
#include <hip/hip_bf16.h>
#include <stdint.h>

// ---------------------------------------------------------------------------
// RandomFeatureAttention: B=4, N=4096, E=1024, H=16, D=64, P_DIM=64, feat=128
// Round 4: GEMM overhaul — XOR-swizzled LDS (kill 16-way bank conflicts),
// LDS-repacked vectorized C epilogue, fused QKV launch (gridDim.z=3),
// direct-read of bf16 inputs (skip cvt when flag==1).
// ---------------------------------------------------------------------------

typedef __bf16 bf16x8 __attribute__((ext_vector_type(8)));
typedef float f32x4 __attribute__((ext_vector_type(4)));

#define AS1 __attribute__((address_space(1)))
#define AS3 __attribute__((address_space(3)))

__device__ __forceinline__ void gl2lds16(const void* g, void* l) {
    __builtin_amdgcn_global_load_lds((const AS1 void*)g, (AS3 void*)l, 16, 0, 0);
}

// ----------------------------- dtype detect --------------------------------
__global__ void detect_kernel(const unsigned short* __restrict__ x,
                              int* __restrict__ flag) {
    __shared__ int s;
    const int lane = threadIdx.x;  // 64 threads
    if (lane == 0) s = 0;
    __syncthreads();
    int cnt = 0;
#pragma unroll
    for (int i = 0; i < 2; ++i) {
        const unsigned short u = x[i * 64 + lane];
        const int e = (u >> 7) & 0xFF;
        cnt += (e >= 117 && e <= 131) ? 1 : 0;
    }
    atomicAdd(&s, cnt);
    __syncthreads();
    if (lane == 0) *flag = (s >= 100) ? 1 : 0;  // 1 = bf16 storage
}

// ----------------------------- convert -------------------------------------
// Only needed when flag==0 (fp32 storage): fp32 -> bf16. No-op if flag==1.
__global__ __launch_bounds__(256) void cvt_kernel(
    const void* __restrict__ src, __hip_bfloat16* __restrict__ dst,
    int n, const int* __restrict__ flag) {
    if (*flag) return;
    const int i = (blockIdx.x * 256 + threadIdx.x) * 8;
    if (i >= n) return;
    const float* s = (const float*)src + i;
    const float4 a = *(const float4*)s;
    const float4 b = *(const float4*)(s + 4);
    union { uint4 u; __hip_bfloat16 h[8]; } pk;
    pk.h[0] = __float2bfloat16(a.x); pk.h[1] = __float2bfloat16(a.y);
    pk.h[2] = __float2bfloat16(a.z); pk.h[3] = __float2bfloat16(a.w);
    pk.h[4] = __float2bfloat16(b.x); pk.h[5] = __float2bfloat16(b.y);
    pk.h[6] = __float2bfloat16(b.z); pk.h[7] = __float2bfloat16(b.w);
    *(uint4*)(dst + i) = pk.u;
}

// ----------------------------- GEMM ----------------------------------------
// C(M,Nd) = A(M,K)@W(Nd,K)^T + bias. Tile 128x128, BK=64, 4 waves (2x2).
// gridDim.z selects (W,bias,out) triple -> QKV fused in one launch.
// LDS k-chunk XOR-swizzle (chunk ^= row&7) on both staging and reads.
static constexpr int GM = 16384, GN = 1024, GK = 1024;

__global__ __launch_bounds__(256) void gemm_bias_kernel(
    const void* __restrict__ Adirect,          // bf16 if flag==1 (may be input x)
    const __hip_bfloat16* __restrict__ Acvt,   // bf16 ws copy  (flag==0)
    const void* __restrict__ W0r, const void* __restrict__ W1r,
    const void* __restrict__ W2r,
    const __hip_bfloat16* __restrict__ W0c, const __hip_bfloat16* __restrict__ W1c,
    const __hip_bfloat16* __restrict__ W2c,
    const void* __restrict__ b0r, const void* __restrict__ b1r,
    const void* __restrict__ b2r,
    void* __restrict__ o0, void* __restrict__ o1, void* __restrict__ o2,
    const int* __restrict__ flag, int last)
{
    __shared__ unsigned short smem[2 * 128 * 64];  // sA | sB ; reused as C-tile
    unsigned short* sA = smem;
    unsigned short* sB = smem + 128 * 64;

    const int tid  = threadIdx.x;
    const int lane = tid & 63;
    const int w    = tid >> 6;
    const int wm   = w >> 1, wn = w & 1;
    const int lr   = lane & 15, lk = lane >> 4;
    const int m0   = blockIdx.y * 128;
    const int n0   = blockIdx.x * 128;
    const int z    = blockIdx.z;
    const int fl   = *flag;

    const __hip_bfloat16* A = fl ? (const __hip_bfloat16*)Adirect : Acvt;
    const void* Wraw = (z == 0) ? W0r : (z == 1) ? W1r : W2r;
    const __hip_bfloat16* Wc = (z == 0) ? W0c : (z == 1) ? W1c : W2c;
    const __hip_bfloat16* W = fl ? (const __hip_bfloat16*)Wraw : Wc;
    const void* bias_raw = (z == 0) ? b0r : (z == 1) ? b1r : b2r;
    void* Cout = (z == 0) ? o0 : (z == 1) ? o1 : o2;

    f32x4 acc[4][4];
#pragma unroll
    for (int i = 0; i < 4; ++i)
#pragma unroll
        for (int j = 0; j < 4; ++j)
            acc[i][j] = (f32x4){0.f, 0.f, 0.f, 0.f};

    const __hip_bfloat16* Ab = A + (size_t)m0 * GK;
    const __hip_bfloat16* Wb = W + (size_t)n0 * GK;

    for (int k0 = 0; k0 < GK; k0 += 64) {
        // stage A,B tiles; global source chunk XOR-swizzled by row&7 so that
        // LDS slot (row,c) holds global chunk c^(row&7)
#pragma unroll
        for (int j = 0; j < 4; ++j) {
            const int chunk = j * 256 + tid;       // 0..1023 == row*8+c
            const int row   = chunk >> 3;
            const int c     = chunk & 7;
            const int cs    = c ^ (row & 7);
            gl2lds16(Ab + (size_t)row * GK + k0 + cs * 8,
                     (char*)sA + (j * 256 + w * 64) * 16);
            gl2lds16(Wb + (size_t)row * GK + k0 + cs * 8,
                     (char*)sB + (j * 256 + w * 64) * 16);
        }
        __syncthreads();
#pragma unroll
        for (int kk = 0; kk < 64; kk += 32) {
            const int jbase = kk >> 3;             // 0 or 4
            const int jj = (jbase + lk) ^ (lr & 7);
            bf16x8 af[4], bfr[4];
#pragma unroll
            for (int i = 0; i < 4; ++i)
                af[i] = *(const bf16x8*)&sA[(wm * 64 + i * 16 + lr) * 64 + jj * 8];
#pragma unroll
            for (int j = 0; j < 4; ++j)
                bfr[j] = *(const bf16x8*)&sB[(wn * 64 + j * 16 + lr) * 64 + jj * 8];
#pragma unroll
            for (int i = 0; i < 4; ++i)
#pragma unroll
                for (int j = 0; j < 4; ++j)
                    acc[i][j] = __builtin_amdgcn_mfma_f32_16x16x32_bf16(
                        af[i], bfr[j], acc[i][j], 0, 0, 0);
        }
        __syncthreads();
    }

    // epilogue. C/D layout: col=lane&15, row=(lane>>4)*4+reg
    const bool f32out = (last != 0) && (fl == 0);
    if (f32out) {
        // rare path (fp32 storage, final GEMM): scalar stores
#pragma unroll
        for (int j = 0; j < 4; ++j) {
            const int col = n0 + wn * 64 + j * 16 + lr;
            const float bv = ((const float*)bias_raw)[col];
#pragma unroll
            for (int i = 0; i < 4; ++i) {
                const int rbase = m0 + wm * 64 + i * 16 + lk * 4;
#pragma unroll
                for (int r = 0; r < 4; ++r)
                    ((float*)Cout)[(size_t)(rbase + r) * GN + col] = acc[i][j][r] + bv;
            }
        }
        return;
    }
    // bf16 path: repack through LDS (swizzled 16B chunks), vectorized stores.
    // sC layout: 128 rows x 16 chunks of 8 bf16; chunk stored at c2^(row&7).
    __hip_bfloat16* sC = (__hip_bfloat16*)smem;
#pragma unroll
    for (int j = 0; j < 4; ++j) {
        const int col = wn * 64 + j * 16 + lr;
        const float bv = fl ? __bfloat162float(((const __hip_bfloat16*)bias_raw)[n0 + col])
                            : ((const float*)bias_raw)[n0 + col];
        const int c2 = col >> 3, o = col & 7;
#pragma unroll
        for (int i = 0; i < 4; ++i) {
            const int rb = wm * 64 + i * 16 + lk * 4;
#pragma unroll
            for (int r = 0; r < 4; ++r) {
                const int row = rb + r;
                const int c2s = c2 ^ (row & 7);
                sC[row * 128 + c2s * 8 + o] = __float2bfloat16(acc[i][j][r] + bv);
            }
        }
    }
    __syncthreads();
    {
        const int row = tid >> 1, hf = tid & 1;
        __hip_bfloat16* dst = (__hip_bfloat16*)Cout + (size_t)(m0 + row) * GN + n0 + hf * 64;
#pragma unroll
        for (int q = 0; q < 8; ++q) {
            const int cc = (hf * 8 + q) ^ (row & 7);
            *(uint4*)(dst + q * 8) = *(const uint4*)&sC[row * 128 + cc * 8];
        }
    }
}

// ----------------------------- shared helpers -------------------------------
__device__ __forceinline__ void load_P(const void* Praw, int f,
                                       __hip_bfloat16* sP, int tid) {
    const int e = tid >> 2, q = tid & 3;
    union { uint4 u[2]; __hip_bfloat16 h[16]; } pk;
    if (f) {
        pk.u[0] = *(const uint4*)((const __hip_bfloat16*)Praw + e * 64 + q * 16);
        pk.u[1] = *(const uint4*)((const __hip_bfloat16*)Praw + e * 64 + q * 16 + 8);
    } else {
        const float* ps = (const float*)Praw + e * 64 + q * 16;
#pragma unroll
        for (int j = 0; j < 16; ++j) pk.h[j] = __float2bfloat16(ps[j]);
    }
    *(uint4*)&sP[e * 72 + q * 16]     = pk.u[0];
    *(uint4*)&sP[e * 72 + q * 16 + 8] = pk.u[1];
}

// ----------------------------- kv kernel -----------------------------------
__global__ __launch_bounds__(256) void kv_kernel(
    const __hip_bfloat16* __restrict__ Km,
    const __hip_bfloat16* __restrict__ Vm,
    const void* __restrict__ Praw,
    float* __restrict__ gKV,
    const int* __restrict__ flag)
{
    __shared__ __hip_bfloat16 sK[64 * 72];     // [n][d]
    __shared__ __hip_bfloat16 sVT[64 * 72];    // [d][n]
    __shared__ __hip_bfloat16 sP[64 * 72];     // [e][d]
    __shared__ __hip_bfloat16 sKFT[128 * 72];  // [e][n]
    __shared__ float sRN[64];

    const int tid  = threadIdx.x;
    const int lane = tid & 63;
    const int w    = tid >> 6;
    const int lr   = lane & 15, lk = lane >> 4;
    const int bh   = blockIdx.y;
    const int b    = bh >> 4, h = bh & 15;
    const int nst  = blockIdx.x * 512;
    const int f    = *flag;

    load_P(Praw, f, sP, tid);

    f32x4 acck[2][4];
#pragma unroll
    for (int i = 0; i < 2; ++i)
#pragma unroll
        for (int j = 0; j < 4; ++j)
            acck[i][j] = (f32x4){0.f, 0.f, 0.f, 0.f};

    for (int s = 0; s < 8; ++s) {
        const int gn0 = nst + s * 64;
        __syncthreads();
        {
            const int n = tid >> 2, q = tid & 3;
            const size_t base = ((size_t)(b * 4096 + gn0 + n)) * 1024 + h * 64 + q * 16;
            uint4 k0 = *(const uint4*)(Km + base);
            uint4 k1 = *(const uint4*)(Km + base + 8);
            *(uint4*)&sK[n * 72 + q * 16]     = k0;
            *(uint4*)&sK[n * 72 + q * 16 + 8] = k1;
            union { uint4 u[2]; __hip_bfloat16 h[16]; } vv;
            vv.u[0] = *(const uint4*)(Vm + base);
            vv.u[1] = *(const uint4*)(Vm + base + 8);
#pragma unroll
            for (int j = 0; j < 16; ++j) sVT[(q * 16 + j) * 72 + n] = vv.h[j];
        }
        __syncthreads();
        {
            const int tl = lane >> 2, q2 = lane & 3;
            const int token = w * 16 + tl;
            union { bf16x8 v; __hip_bfloat16 h[8]; } a0, a1;
            a0.v = *(const bf16x8*)&sK[token * 72 + q2 * 16];
            a1.v = *(const bf16x8*)&sK[token * 72 + q2 * 16 + 8];
            float ss = 0.f;
#pragma unroll
            for (int j = 0; j < 8; ++j) {
                float x0 = __bfloat162float(a0.h[j]); ss += x0 * x0;
                float x1 = __bfloat162float(a1.h[j]); ss += x1 * x1;
            }
            ss += __shfl_xor(ss, 1, 64);
            ss += __shfl_xor(ss, 2, 64);
            if (q2 == 0) sRN[token] = 2.0f / (sqrtf(ss) + 1e-4f);
        }
        __syncthreads();
        {
            bf16x8 afr0 = *(const bf16x8*)&sK[(w * 16 + lr) * 72 + lk * 8];
            bf16x8 afr1 = *(const bf16x8*)&sK[(w * 16 + lr) * 72 + 32 + lk * 8];
            float rn[4];
#pragma unroll
            for (int r = 0; r < 4; ++r) rn[r] = sRN[w * 16 + lk * 4 + r];
#pragma unroll
            for (int eb = 0; eb < 4; ++eb) {
                f32x4 pa = (f32x4){0.f, 0.f, 0.f, 0.f};
                bf16x8 b0 = *(const bf16x8*)&sP[(eb * 16 + lr) * 72 + lk * 8];
                bf16x8 b1 = *(const bf16x8*)&sP[(eb * 16 + lr) * 72 + 32 + lk * 8];
                pa = __builtin_amdgcn_mfma_f32_16x16x32_bf16(afr0, b0, pa, 0, 0, 0);
                pa = __builtin_amdgcn_mfma_f32_16x16x32_bf16(afr1, b1, pa, 0, 0, 0);
                const int col = eb * 16 + lr;
#pragma unroll
                for (int r = 0; r < 4; ++r) {
                    const int row = w * 16 + lk * 4 + r;
                    float sv, cv;
                    __sincosf(pa[r] * rn[r], &sv, &cv);
                    sKFT[col * 72 + row]        = __float2bfloat16(sv * 0.125f);
                    sKFT[(col + 64) * 72 + row] = __float2bfloat16(cv * 0.125f);
                }
            }
        }
        __syncthreads();
#pragma unroll
        for (int ks = 0; ks < 2; ++ks) {
            bf16x8 a2[2], b2[4];
            a2[0] = *(const bf16x8*)&sKFT[(w * 16 + lr) * 72 + ks * 32 + lk * 8];
            a2[1] = *(const bf16x8*)&sKFT[((w + 4) * 16 + lr) * 72 + ks * 32 + lk * 8];
#pragma unroll
            for (int db = 0; db < 4; ++db)
                b2[db] = *(const bf16x8*)&sVT[(db * 16 + lr) * 72 + ks * 32 + lk * 8];
#pragma unroll
            for (int i = 0; i < 2; ++i)
#pragma unroll
                for (int db = 0; db < 4; ++db)
                    acck[i][db] = __builtin_amdgcn_mfma_f32_16x16x32_bf16(
                        a2[i], b2[db], acck[i][db], 0, 0, 0);
        }
    }

    float* out = gKV + (size_t)bh * 8192;
#pragma unroll
    for (int i = 0; i < 2; ++i)
#pragma unroll
        for (int db = 0; db < 4; ++db)
#pragma unroll
            for (int r = 0; r < 4; ++r) {
                const int e = (w + 4 * i) * 16 + lk * 4 + r;
                const int d = db * 16 + lr;
                atomicAdd(out + e * 64 + d, acck[i][db][r]);
            }
}

// ----------------------------- o kernel ------------------------------------
__global__ __launch_bounds__(256) void o_kernel(
    const __hip_bfloat16* __restrict__ Qm,
    const void* __restrict__ Praw,
    const float* __restrict__ gKV,
    __hip_bfloat16* __restrict__ O,
    const int* __restrict__ flag)
{
    __shared__ __hip_bfloat16 sQ[64 * 72];     // [n][d], reused as o-tile
    __shared__ __hip_bfloat16 sP[64 * 72];     // [e][d]
    __shared__ __hip_bfloat16 sQF[64 * 136];   // [n][e]
    __shared__ __hip_bfloat16 sKVT[64 * 136];  // [d][e]
    __shared__ float sRN[64];

    const int tid  = threadIdx.x;
    const int lane = tid & 63;
    const int w    = tid >> 6;
    const int lr   = lane & 15, lk = lane >> 4;
    const int bh   = blockIdx.y;
    const int b    = bh >> 4, h = bh & 15;
    const int nst  = blockIdx.x * 256;
    const int f    = *flag;

    load_P(Praw, f, sP, tid);
    {
        const float* kvsrc = gKV + (size_t)bh * 8192;
        for (int t = tid; t < 8192; t += 256) {
            const int e = t >> 6, d = t & 63;
            sKVT[d * 136 + e] = __float2bfloat16(kvsrc[t]);
        }
    }

    for (int s = 0; s < 4; ++s) {
        const int gn0 = nst + s * 64;
        __syncthreads();
        {
            const int n = tid >> 2, q = tid & 3;
            const size_t base = ((size_t)(b * 4096 + gn0 + n)) * 1024 + h * 64 + q * 16;
            uint4 q0 = *(const uint4*)(Qm + base);
            uint4 q1 = *(const uint4*)(Qm + base + 8);
            *(uint4*)&sQ[n * 72 + q * 16]     = q0;
            *(uint4*)&sQ[n * 72 + q * 16 + 8] = q1;
        }
        __syncthreads();
        {
            const int tl = lane >> 2, q2 = lane & 3;
            const int token = w * 16 + tl;
            union { bf16x8 v; __hip_bfloat16 h[8]; } a0, a1;
            a0.v = *(const bf16x8*)&sQ[token * 72 + q2 * 16];
            a1.v = *(const bf16x8*)&sQ[token * 72 + q2 * 16 + 8];
            float ss = 0.f;
#pragma unroll
            for (int j = 0; j < 8; ++j) {
                float x0 = __bfloat162float(a0.h[j]); ss += x0 * x0;
                float x1 = __bfloat162float(a1.h[j]); ss += x1 * x1;
            }
            ss += __shfl_xor(ss, 1, 64);
            ss += __shfl_xor(ss, 2, 64);
            if (q2 == 0) sRN[token] = 2.0f / (sqrtf(ss) + 1e-4f);
        }
        __syncthreads();
        {
            bf16x8 afr0 = *(const bf16x8*)&sQ[(w * 16 + lr) * 72 + lk * 8];
            bf16x8 afr1 = *(const bf16x8*)&sQ[(w * 16 + lr) * 72 + 32 + lk * 8];
            float rn[4];
#pragma unroll
            for (int r = 0; r < 4; ++r) rn[r] = sRN[w * 16 + lk * 4 + r];
#pragma unroll
            for (int eb = 0; eb < 4; ++eb) {
                f32x4 pa = (f32x4){0.f, 0.f, 0.f, 0.f};
                bf16x8 b0 = *(const bf16x8*)&sP[(eb * 16 + lr) * 72 + lk * 8];
                bf16x8 b1 = *(const bf16x8*)&sP[(eb * 16 + lr) * 72 + 32 + lk * 8];
                pa = __builtin_amdgcn_mfma_f32_16x16x32_bf16(afr0, b0, pa, 0, 0, 0);
                pa = __builtin_amdgcn_mfma_f32_16x16x32_bf16(afr1, b1, pa, 0, 0, 0);
                const int col = eb * 16 + lr;
#pragma unroll
                for (int r = 0; r < 4; ++r) {
                    const int row = w * 16 + lk * 4 + r;
                    float sv, cv;
                    __sincosf(pa[r] * rn[r], &sv, &cv);
                    sQF[row * 136 + col]      = __float2bfloat16(sv * 0.125f);
                    sQF[row * 136 + 64 + col] = __float2bfloat16(cv * 0.125f);
                }
            }
        }
        __syncthreads();
        f32x4 oacc[4];
#pragma unroll
        for (int nb = 0; nb < 4; ++nb) oacc[nb] = (f32x4){0.f, 0.f, 0.f, 0.f};
#pragma unroll
        for (int ks = 0; ks < 4; ++ks) {
            bf16x8 aa = *(const bf16x8*)&sQF[(w * 16 + lr) * 136 + ks * 32 + lk * 8];
#pragma unroll
            for (int nb = 0; nb < 4; ++nb) {
                bf16x8 bb = *(const bf16x8*)&sKVT[(nb * 16 + lr) * 136 + ks * 32 + lk * 8];
                oacc[nb] = __builtin_amdgcn_mfma_f32_16x16x32_bf16(aa, bb, oacc[nb], 0, 0, 0);
            }
        }
#pragma unroll
        for (int nb = 0; nb < 4; ++nb)
#pragma unroll
            for (int r = 0; r < 4; ++r)
                sQ[(w * 16 + lk * 4 + r) * 72 + nb * 16 + lr] =
                    __float2bfloat16(oacc[nb][r]);
        __syncthreads();
        {
            const int n = tid >> 2, q = tid & 3;
            uint4 o0 = *(uint4*)&sQ[n * 72 + q * 16];
            uint4 o1 = *(uint4*)&sQ[n * 72 + q * 16 + 8];
            const size_t obase = ((size_t)(b * 4096 + gn0 + n)) * 1024 + h * 64 + q * 16;
            *(uint4*)(O + obase)     = o0;
            *(uint4*)(O + obase + 8) = o1;
        }
    }
}

// ----------------------------- launcher ------------------------------------
extern "C" void kernel_launch(void* const* d_in, const int* in_sizes, int n_in,
                              void* d_out, int out_size, void* d_ws, size_t ws_size,
                              hipStream_t stream)
{
    (void)in_sizes; (void)n_in; (void)out_size;
    const void* x  = d_in[0];
    const void* Wq = d_in[1];
    const void* bq = d_in[2];
    const void* Wk = d_in[3];
    const void* bk = d_in[4];
    const void* Wv = d_in[5];
    const void* bv = d_in[6];
    const void* Wo = d_in[7];
    const void* bo = d_in[8];
    const void* P  = d_in[9];

    constexpr size_t XE = (size_t)GM * GN;   // 16777216
    constexpr size_t WE = (size_t)GN * GK;   // 1048576
    constexpr size_t KVE = (size_t)64 * 128 * 64;

    __hip_bfloat16* xb  = (__hip_bfloat16*)d_ws;
    __hip_bfloat16* wqb = xb + XE;
    __hip_bfloat16* wkb = wqb + WE;
    __hip_bfloat16* wvb = wkb + WE;
    __hip_bfloat16* wob = wvb + WE;
    __hip_bfloat16* R1  = wob + WE;          // K, later O
    __hip_bfloat16* R2  = R1 + XE;           // V (fused) / V then Q (fallback)
    // fused path only:
    __hip_bfloat16* R3  = R2 + XE;           // Q

    const size_t need_fused = ((4 * XE + 4 * WE) * 2 + KVE * 4 + 256);
    const bool fused = ws_size >= need_fused;

    float* gKV;
    int* flag;
    if (fused) {
        gKV = (float*)(R3 + XE);
        flag = (int*)(gKV + KVE);
    } else {
        gKV = (float*)(R2 + XE);
        flag = (int*)(gKV + KVE);
    }

    dim3 blk(256);
    hipLaunchKernelGGL(detect_kernel, dim3(1), dim3(64), 0, stream,
                       (const unsigned short*)x, flag);
    hipMemsetAsync(gKV, 0, KVE * sizeof(float), stream);

    // converts are no-ops when flag==1 (GEMM reads inputs directly)
    hipLaunchKernelGGL(cvt_kernel, dim3(8192), blk, 0, stream, x,  xb,  (int)XE, flag);
    hipLaunchKernelGGL(cvt_kernel, dim3(512),  blk, 0, stream, Wq, wqb, (int)WE, flag);
    hipLaunchKernelGGL(cvt_kernel, dim3(512),  blk, 0, stream, Wk, wkb, (int)WE, flag);
    hipLaunchKernelGGL(cvt_kernel, dim3(512),  blk, 0, stream, Wv, wvb, (int)WE, flag);
    hipLaunchKernelGGL(cvt_kernel, dim3(512),  blk, 0, stream, Wo, wob, (int)WE, flag);

    if (fused) {
        // QKV in one launch: z=0 K->R1, z=1 V->R2, z=2 Q->R3
        hipLaunchKernelGGL(gemm_bias_kernel, dim3(GN / 128, GM / 128, 3), blk, 0, stream,
                           x, xb, Wk, Wv, Wq, wkb, wvb, wqb, bk, bv, bq,
                           R1, R2, R3, flag, 0);
        hipLaunchKernelGGL(kv_kernel, dim3(8, 64), blk, 0, stream, R1, R2, P, gKV, flag);
        hipLaunchKernelGGL(o_kernel, dim3(16, 64), blk, 0, stream, R3, P, gKV, R1, flag);
        hipLaunchKernelGGL(gemm_bias_kernel, dim3(GN / 128, GM / 128, 1), blk, 0, stream,
                           R1, R1, Wo, Wo, Wo, wob, wob, wob, bo, bo, bo,
                           d_out, d_out, d_out, flag, 1);
    } else {
        dim3 gg(GN / 128, GM / 128, 1);
        hipLaunchKernelGGL(gemm_bias_kernel, gg, blk, 0, stream,
                           x, xb, Wk, Wk, Wk, wkb, wkb, wkb, bk, bk, bk,
                           R1, R1, R1, flag, 0);
        hipLaunchKernelGGL(gemm_bias_kernel, gg, blk, 0, stream,
                           x, xb, Wv, Wv, Wv, wvb, wvb, wvb, bv, bv, bv,
                           R2, R2, R2, flag, 0);
        hipLaunchKernelGGL(kv_kernel, dim3(8, 64), blk, 0, stream, R1, R2, P, gKV, flag);
        hipLaunchKernelGGL(gemm_bias_kernel, gg, blk, 0, stream,
                           x, xb, Wq, Wq, Wq, wqb, wqb, wqb, bq, bq, bq,
                           R2, R2, R2, flag, 0);
        hipLaunchKernelGGL(o_kernel, dim3(16, 64), blk, 0, stream, R2, P, gKV, R1, flag);
        hipLaunchKernelGGL(gemm_bias_kernel, gg, blk, 0, stream,
                           R1, R1, Wo, Wo, Wo, wob, wob, wob, bo, bo, bo,
                           d_out, d_out, d_out, flag, 1);
    }
}

// Round 5
// 413.112 us; speedup vs baseline: 1.7793x; 1.0322x over previous
//
#include <hip/hip_runtime.h>
#include <hip/hip_bf16.h>
#include <stdint.h>

// ---------------------------------------------------------------------------
// RandomFeatureAttention: B=4, N=4096, E=1024, H=16, D=64, P_DIM=64, feat=128
// Round 5: XCD-pinned GEMM swizzle (x-slab = 4MB = one L2); kv/o pipelined
// (register-norm folded into staging, global prefetch, kv grid doubled).
// ---------------------------------------------------------------------------

typedef __bf16 bf16x8 __attribute__((ext_vector_type(8)));
typedef float f32x4 __attribute__((ext_vector_type(4)));

#define AS1 __attribute__((address_space(1)))
#define AS3 __attribute__((address_space(3)))

__device__ __forceinline__ void gl2lds16(const void* g, void* l) {
    __builtin_amdgcn_global_load_lds((const AS1 void*)g, (AS3 void*)l, 16, 0, 0);
}

// ----------------------------- dtype detect --------------------------------
__global__ void detect_kernel(const unsigned short* __restrict__ x,
                              int* __restrict__ flag) {
    __shared__ int s;
    const int lane = threadIdx.x;  // 64 threads
    if (lane == 0) s = 0;
    __syncthreads();
    int cnt = 0;
#pragma unroll
    for (int i = 0; i < 2; ++i) {
        const unsigned short u = x[i * 64 + lane];
        const int e = (u >> 7) & 0xFF;
        cnt += (e >= 117 && e <= 131) ? 1 : 0;
    }
    atomicAdd(&s, cnt);
    __syncthreads();
    if (lane == 0) *flag = (s >= 100) ? 1 : 0;  // 1 = bf16 storage
}

// ----------------------------- convert -------------------------------------
__global__ __launch_bounds__(256) void cvt_kernel(
    const void* __restrict__ src, __hip_bfloat16* __restrict__ dst,
    int n, const int* __restrict__ flag) {
    if (*flag) return;
    const int i = (blockIdx.x * 256 + threadIdx.x) * 8;
    if (i >= n) return;
    const float* s = (const float*)src + i;
    const float4 a = *(const float4*)s;
    const float4 b = *(const float4*)(s + 4);
    union { uint4 u; __hip_bfloat16 h[8]; } pk;
    pk.h[0] = __float2bfloat16(a.x); pk.h[1] = __float2bfloat16(a.y);
    pk.h[2] = __float2bfloat16(a.z); pk.h[3] = __float2bfloat16(a.w);
    pk.h[4] = __float2bfloat16(b.x); pk.h[5] = __float2bfloat16(b.y);
    pk.h[6] = __float2bfloat16(b.z); pk.h[7] = __float2bfloat16(b.w);
    *(uint4*)(dst + i) = pk.u;
}

// ----------------------------- GEMM ----------------------------------------
// C(M,Nd) = A(M,K)@W(Nd,K)^T + bias. Tile 128x128, BK=64, 4 waves (2x2).
// 1-D grid, XCD-pinned swizzle: xcd=id&7 owns m-blocks [xcd*16, xcd*16+16)
// (x slab 4MB = one XCD L2); (nx,z) phases iterate with x hot in L2.
static constexpr int GM = 16384, GN = 1024, GK = 1024;

__global__ __launch_bounds__(256) void gemm_bias_kernel(
    const void* __restrict__ Adirect,
    const __hip_bfloat16* __restrict__ Acvt,
    const void* __restrict__ W0r, const void* __restrict__ W1r,
    const void* __restrict__ W2r,
    const __hip_bfloat16* __restrict__ W0c, const __hip_bfloat16* __restrict__ W1c,
    const __hip_bfloat16* __restrict__ W2c,
    const void* __restrict__ b0r, const void* __restrict__ b1r,
    const void* __restrict__ b2r,
    void* __restrict__ o0, void* __restrict__ o1, void* __restrict__ o2,
    const int* __restrict__ flag, int last)
{
    __shared__ unsigned short smem[2 * 128 * 64];  // sA | sB ; reused as C-tile
    unsigned short* sA = smem;
    unsigned short* sB = smem + 128 * 64;

    const int tid  = threadIdx.x;
    const int lane = tid & 63;
    const int w    = tid >> 6;
    const int wm   = w >> 1, wn = w & 1;
    const int lr   = lane & 15, lk = lane >> 4;

    // XCD-pinned swizzle (grid must be divisible by 128)
    const int id    = blockIdx.x;
    const int xcd   = id & 7;
    const int slot  = id >> 3;
    const int mslot = slot & 15;
    const int rest  = slot >> 4;      // nx + 8*z
    const int m0    = (xcd * 16 + mslot) * 128;
    const int n0    = (rest & 7) * 128;
    const int z     = rest >> 3;
    const int fl    = *flag;

    const __hip_bfloat16* A = fl ? (const __hip_bfloat16*)Adirect : Acvt;
    const void* Wraw = (z == 0) ? W0r : (z == 1) ? W1r : W2r;
    const __hip_bfloat16* Wc = (z == 0) ? W0c : (z == 1) ? W1c : W2c;
    const __hip_bfloat16* W = fl ? (const __hip_bfloat16*)Wraw : Wc;
    const void* bias_raw = (z == 0) ? b0r : (z == 1) ? b1r : b2r;
    void* Cout = (z == 0) ? o0 : (z == 1) ? o1 : o2;

    f32x4 acc[4][4];
#pragma unroll
    for (int i = 0; i < 4; ++i)
#pragma unroll
        for (int j = 0; j < 4; ++j)
            acc[i][j] = (f32x4){0.f, 0.f, 0.f, 0.f};

    const __hip_bfloat16* Ab = A + (size_t)m0 * GK;
    const __hip_bfloat16* Wb = W + (size_t)n0 * GK;

    for (int k0 = 0; k0 < GK; k0 += 64) {
#pragma unroll
        for (int j = 0; j < 4; ++j) {
            const int chunk = j * 256 + tid;       // row*8+c
            const int row   = chunk >> 3;
            const int c     = chunk & 7;
            const int cs    = c ^ (row & 7);
            gl2lds16(Ab + (size_t)row * GK + k0 + cs * 8,
                     (char*)sA + (j * 256 + w * 64) * 16);
            gl2lds16(Wb + (size_t)row * GK + k0 + cs * 8,
                     (char*)sB + (j * 256 + w * 64) * 16);
        }
        __syncthreads();
#pragma unroll
        for (int kk = 0; kk < 64; kk += 32) {
            const int jbase = kk >> 3;
            const int jj = (jbase + lk) ^ (lr & 7);
            bf16x8 af[4], bfr[4];
#pragma unroll
            for (int i = 0; i < 4; ++i)
                af[i] = *(const bf16x8*)&sA[(wm * 64 + i * 16 + lr) * 64 + jj * 8];
#pragma unroll
            for (int j = 0; j < 4; ++j)
                bfr[j] = *(const bf16x8*)&sB[(wn * 64 + j * 16 + lr) * 64 + jj * 8];
#pragma unroll
            for (int i = 0; i < 4; ++i)
#pragma unroll
                for (int j = 0; j < 4; ++j)
                    acc[i][j] = __builtin_amdgcn_mfma_f32_16x16x32_bf16(
                        af[i], bfr[j], acc[i][j], 0, 0, 0);
        }
        __syncthreads();
    }

    const bool f32out = (last != 0) && (fl == 0);
    if (f32out) {
#pragma unroll
        for (int j = 0; j < 4; ++j) {
            const int col = n0 + wn * 64 + j * 16 + lr;
            const float bv = ((const float*)bias_raw)[col];
#pragma unroll
            for (int i = 0; i < 4; ++i) {
                const int rbase = m0 + wm * 64 + i * 16 + lk * 4;
#pragma unroll
                for (int r = 0; r < 4; ++r)
                    ((float*)Cout)[(size_t)(rbase + r) * GN + col] = acc[i][j][r] + bv;
            }
        }
        return;
    }
    __hip_bfloat16* sC = (__hip_bfloat16*)smem;
#pragma unroll
    for (int j = 0; j < 4; ++j) {
        const int col = wn * 64 + j * 16 + lr;
        const float bv = fl ? __bfloat162float(((const __hip_bfloat16*)bias_raw)[n0 + col])
                            : ((const float*)bias_raw)[n0 + col];
        const int c2 = col >> 3, o = col & 7;
#pragma unroll
        for (int i = 0; i < 4; ++i) {
            const int rb = wm * 64 + i * 16 + lk * 4;
#pragma unroll
            for (int r = 0; r < 4; ++r) {
                const int row = rb + r;
                const int c2s = c2 ^ (row & 7);
                sC[row * 128 + c2s * 8 + o] = __float2bfloat16(acc[i][j][r] + bv);
            }
        }
    }
    __syncthreads();
    {
        const int row = tid >> 1, hf = tid & 1;
        __hip_bfloat16* dst = (__hip_bfloat16*)Cout + (size_t)(m0 + row) * GN + n0 + hf * 64;
#pragma unroll
        for (int q = 0; q < 8; ++q) {
            const int cc = (hf * 8 + q) ^ (row & 7);
            *(uint4*)(dst + q * 8) = *(const uint4*)&sC[row * 128 + cc * 8];
        }
    }
}

// ----------------------------- shared helpers -------------------------------
__device__ __forceinline__ void load_P(const void* Praw, int f,
                                       __hip_bfloat16* sP, int tid) {
    const int e = tid >> 2, q = tid & 3;
    union { uint4 u[2]; __hip_bfloat16 h[16]; } pk;
    if (f) {
        pk.u[0] = *(const uint4*)((const __hip_bfloat16*)Praw + e * 64 + q * 16);
        pk.u[1] = *(const uint4*)((const __hip_bfloat16*)Praw + e * 64 + q * 16 + 8);
    } else {
        const float* ps = (const float*)Praw + e * 64 + q * 16;
#pragma unroll
        for (int j = 0; j < 16; ++j) pk.h[j] = __float2bfloat16(ps[j]);
    }
    *(uint4*)&sP[e * 72 + q * 16]     = pk.u[0];
    *(uint4*)&sP[e * 72 + q * 16 + 8] = pk.u[1];
}

// sumsq of 16 bf16 held in two uint4 registers
__device__ __forceinline__ float sumsq16(uint4 a, uint4 b) {
    union { uint4 u; __hip_bfloat16 h[8]; } x0, x1;
    x0.u = a; x1.u = b;
    float ss = 0.f;
#pragma unroll
    for (int j = 0; j < 8; ++j) {
        float v0 = __bfloat162float(x0.h[j]); ss += v0 * v0;
        float v1 = __bfloat162float(x1.h[j]); ss += v1 * v1;
    }
    return ss;
}

// ----------------------------- kv kernel -----------------------------------
// grid (16, 64): 256-token chunk per block, 4 iters of 64 tokens.
// Pipelined: reg-norm in staging, next-iter global prefetch.
__global__ __launch_bounds__(256) void kv_kernel(
    const __hip_bfloat16* __restrict__ Km,
    const __hip_bfloat16* __restrict__ Vm,
    const void* __restrict__ Praw,
    float* __restrict__ gKV,
    const int* __restrict__ flag)
{
    __shared__ __hip_bfloat16 sK[64 * 72];     // [n][d]
    __shared__ __hip_bfloat16 sVT[64 * 72];    // [d][n]
    __shared__ __hip_bfloat16 sP[64 * 72];     // [e][d]
    __shared__ __hip_bfloat16 sKFT[128 * 72];  // [e][n]
    __shared__ float sRN[64];

    const int tid  = threadIdx.x;
    const int lane = tid & 63;
    const int w    = tid >> 6;
    const int lr   = lane & 15, lk = lane >> 4;
    const int bh   = blockIdx.y;
    const int b    = bh >> 4, h = bh & 15;
    const int nst  = blockIdx.x * 256;
    const int f    = *flag;
    const int n    = tid >> 2, q2 = tid & 3;   // staging ownership

    load_P(Praw, f, sP, tid);

    f32x4 acck[2][4];
#pragma unroll
    for (int i = 0; i < 2; ++i)
#pragma unroll
        for (int j = 0; j < 4; ++j)
            acck[i][j] = (f32x4){0.f, 0.f, 0.f, 0.f};

    // prefetch s=0
    size_t base = ((size_t)(b * 4096 + nst + n)) * 1024 + h * 64 + q2 * 16;
    uint4 ka = *(const uint4*)(Km + base), kb = *(const uint4*)(Km + base + 8);
    uint4 va = *(const uint4*)(Vm + base), vb = *(const uint4*)(Vm + base + 8);

    for (int s = 0; s < 4; ++s) {
        __syncthreads();  // LDS consumers of previous iter done (covers P load s==0)
        // stage K [n][d], V^T [d][n]; norm from registers
        *(uint4*)&sK[n * 72 + q2 * 16]     = ka;
        *(uint4*)&sK[n * 72 + q2 * 16 + 8] = kb;
        {
            union { uint4 u[2]; __hip_bfloat16 h[16]; } vv;
            vv.u[0] = va; vv.u[1] = vb;
#pragma unroll
            for (int j = 0; j < 16; ++j) sVT[(q2 * 16 + j) * 72 + n] = vv.h[j];
        }
        {
            float ss = sumsq16(ka, kb);
            ss += __shfl_xor(ss, 1, 64);
            ss += __shfl_xor(ss, 2, 64);
            if (q2 == 0) sRN[n & 63] = 2.0f / (sqrtf(ss) + 1e-4f);  // scale=H^0.25
        }
        // prefetch s+1 (latency overlaps proj + kv MFMA below)
        if (s < 3) {
            base = ((size_t)(b * 4096 + nst + (s + 1) * 64 + n)) * 1024 + h * 64 + q2 * 16;
            ka = *(const uint4*)(Km + base); kb = *(const uint4*)(Km + base + 8);
            va = *(const uint4*)(Vm + base); vb = *(const uint4*)(Vm + base + 8);
        }
        __syncthreads();
        // projection MFMA + sincos -> sKFT
        {
            bf16x8 afr0 = *(const bf16x8*)&sK[(w * 16 + lr) * 72 + lk * 8];
            bf16x8 afr1 = *(const bf16x8*)&sK[(w * 16 + lr) * 72 + 32 + lk * 8];
            float rn[4];
#pragma unroll
            for (int r = 0; r < 4; ++r) rn[r] = sRN[w * 16 + lk * 4 + r];
#pragma unroll
            for (int eb = 0; eb < 4; ++eb) {
                f32x4 pa = (f32x4){0.f, 0.f, 0.f, 0.f};
                bf16x8 b0 = *(const bf16x8*)&sP[(eb * 16 + lr) * 72 + lk * 8];
                bf16x8 b1 = *(const bf16x8*)&sP[(eb * 16 + lr) * 72 + 32 + lk * 8];
                pa = __builtin_amdgcn_mfma_f32_16x16x32_bf16(afr0, b0, pa, 0, 0, 0);
                pa = __builtin_amdgcn_mfma_f32_16x16x32_bf16(afr1, b1, pa, 0, 0, 0);
                const int col = eb * 16 + lr;
#pragma unroll
                for (int r = 0; r < 4; ++r) {
                    const int row = w * 16 + lk * 4 + r;
                    float sv, cv;
                    __sincosf(pa[r] * rn[r], &sv, &cv);
                    sKFT[col * 72 + row]        = __float2bfloat16(sv * 0.125f);
                    sKFT[(col + 64) * 72 + row] = __float2bfloat16(cv * 0.125f);
                }
            }
        }
        __syncthreads();
        // kv MFMA: M=128(e) x N=64(d) x K=64(n)
#pragma unroll
        for (int ks = 0; ks < 2; ++ks) {
            bf16x8 a2[2], b2[4];
            a2[0] = *(const bf16x8*)&sKFT[(w * 16 + lr) * 72 + ks * 32 + lk * 8];
            a2[1] = *(const bf16x8*)&sKFT[((w + 4) * 16 + lr) * 72 + ks * 32 + lk * 8];
#pragma unroll
            for (int db = 0; db < 4; ++db)
                b2[db] = *(const bf16x8*)&sVT[(db * 16 + lr) * 72 + ks * 32 + lk * 8];
#pragma unroll
            for (int i = 0; i < 2; ++i)
#pragma unroll
                for (int db = 0; db < 4; ++db)
                    acck[i][db] = __builtin_amdgcn_mfma_f32_16x16x32_bf16(
                        a2[i], b2[db], acck[i][db], 0, 0, 0);
        }
    }

    float* out = gKV + (size_t)bh * 8192;
#pragma unroll
    for (int i = 0; i < 2; ++i)
#pragma unroll
        for (int db = 0; db < 4; ++db)
#pragma unroll
            for (int r = 0; r < 4; ++r) {
                const int e = (w + 4 * i) * 16 + lk * 4 + r;
                const int d = db * 16 + lr;
                atomicAdd(out + e * 64 + d, acck[i][db][r]);
            }
}

// ----------------------------- o kernel ------------------------------------
// grid (16, 64): 256-token chunk, pipelined like kv_kernel.
__global__ __launch_bounds__(256) void o_kernel(
    const __hip_bfloat16* __restrict__ Qm,
    const void* __restrict__ Praw,
    const float* __restrict__ gKV,
    __hip_bfloat16* __restrict__ O,
    const int* __restrict__ flag)
{
    __shared__ __hip_bfloat16 sQ[64 * 72];     // [n][d], reused as o-tile
    __shared__ __hip_bfloat16 sP[64 * 72];     // [e][d]
    __shared__ __hip_bfloat16 sQF[64 * 136];   // [n][e]
    __shared__ __hip_bfloat16 sKVT[64 * 136];  // [d][e]
    __shared__ float sRN[64];

    const int tid  = threadIdx.x;
    const int lane = tid & 63;
    const int w    = tid >> 6;
    const int lr   = lane & 15, lk = lane >> 4;
    const int bh   = blockIdx.y;
    const int b    = bh >> 4, h = bh & 15;
    const int nst  = blockIdx.x * 256;
    const int f    = *flag;
    const int n    = tid >> 2, q2 = tid & 3;

    load_P(Praw, f, sP, tid);
    {
        const float* kvsrc = gKV + (size_t)bh * 8192;
        for (int t = tid; t < 8192; t += 256) {
            const int e = t >> 6, d = t & 63;
            sKVT[d * 136 + e] = __float2bfloat16(kvsrc[t]);
        }
    }

    size_t base = ((size_t)(b * 4096 + nst + n)) * 1024 + h * 64 + q2 * 16;
    uint4 qa = *(const uint4*)(Qm + base), qb = *(const uint4*)(Qm + base + 8);

    for (int s = 0; s < 4; ++s) {
        const int gn0 = nst + s * 64;
        __syncthreads();  // prev-iter store of sQ done (covers sP/sKVT loads s==0)
        *(uint4*)&sQ[n * 72 + q2 * 16]     = qa;
        *(uint4*)&sQ[n * 72 + q2 * 16 + 8] = qb;
        {
            float ss = sumsq16(qa, qb);
            ss += __shfl_xor(ss, 1, 64);
            ss += __shfl_xor(ss, 2, 64);
            if (q2 == 0) sRN[n & 63] = 2.0f / (sqrtf(ss) + 1e-4f);
        }
        if (s < 3) {
            base = ((size_t)(b * 4096 + nst + (s + 1) * 64 + n)) * 1024 + h * 64 + q2 * 16;
            qa = *(const uint4*)(Qm + base); qb = *(const uint4*)(Qm + base + 8);
        }
        __syncthreads();
        {
            bf16x8 afr0 = *(const bf16x8*)&sQ[(w * 16 + lr) * 72 + lk * 8];
            bf16x8 afr1 = *(const bf16x8*)&sQ[(w * 16 + lr) * 72 + 32 + lk * 8];
            float rn[4];
#pragma unroll
            for (int r = 0; r < 4; ++r) rn[r] = sRN[w * 16 + lk * 4 + r];
#pragma unroll
            for (int eb = 0; eb < 4; ++eb) {
                f32x4 pa = (f32x4){0.f, 0.f, 0.f, 0.f};
                bf16x8 b0 = *(const bf16x8*)&sP[(eb * 16 + lr) * 72 + lk * 8];
                bf16x8 b1 = *(const bf16x8*)&sP[(eb * 16 + lr) * 72 + 32 + lk * 8];
                pa = __builtin_amdgcn_mfma_f32_16x16x32_bf16(afr0, b0, pa, 0, 0, 0);
                pa = __builtin_amdgcn_mfma_f32_16x16x32_bf16(afr1, b1, pa, 0, 0, 0);
                const int col = eb * 16 + lr;
#pragma unroll
                for (int r = 0; r < 4; ++r) {
                    const int row = w * 16 + lk * 4 + r;
                    float sv, cv;
                    __sincosf(pa[r] * rn[r], &sv, &cv);
                    sQF[row * 136 + col]      = __float2bfloat16(sv * 0.125f);
                    sQF[row * 136 + 64 + col] = __float2bfloat16(cv * 0.125f);
                }
            }
        }
        __syncthreads();
        f32x4 oacc[4];
#pragma unroll
        for (int nb = 0; nb < 4; ++nb) oacc[nb] = (f32x4){0.f, 0.f, 0.f, 0.f};
#pragma unroll
        for (int ks = 0; ks < 4; ++ks) {
            bf16x8 aa = *(const bf16x8*)&sQF[(w * 16 + lr) * 136 + ks * 32 + lk * 8];
#pragma unroll
            for (int nb = 0; nb < 4; ++nb) {
                bf16x8 bb = *(const bf16x8*)&sKVT[(nb * 16 + lr) * 136 + ks * 32 + lk * 8];
                oacc[nb] = __builtin_amdgcn_mfma_f32_16x16x32_bf16(aa, bb, oacc[nb], 0, 0, 0);
            }
        }
        // o-tile to sQ (safe: proj phase done with sQ), then vector store
#pragma unroll
        for (int nb = 0; nb < 4; ++nb)
#pragma unroll
            for (int r = 0; r < 4; ++r)
                sQ[(w * 16 + lk * 4 + r) * 72 + nb * 16 + lr] =
                    __float2bfloat16(oacc[nb][r]);
        __syncthreads();
        {
            uint4 o0 = *(uint4*)&sQ[n * 72 + q2 * 16];
            uint4 o1 = *(uint4*)&sQ[n * 72 + q2 * 16 + 8];
            const size_t obase = ((size_t)(b * 4096 + gn0 + n)) * 1024 + h * 64 + q2 * 16;
            *(uint4*)(O + obase)     = o0;
            *(uint4*)(O + obase + 8) = o1;
        }
    }
}

// ----------------------------- launcher ------------------------------------
extern "C" void kernel_launch(void* const* d_in, const int* in_sizes, int n_in,
                              void* d_out, int out_size, void* d_ws, size_t ws_size,
                              hipStream_t stream)
{
    (void)in_sizes; (void)n_in; (void)out_size;
    const void* x  = d_in[0];
    const void* Wq = d_in[1];
    const void* bq = d_in[2];
    const void* Wk = d_in[3];
    const void* bk = d_in[4];
    const void* Wv = d_in[5];
    const void* bv = d_in[6];
    const void* Wo = d_in[7];
    const void* bo = d_in[8];
    const void* P  = d_in[9];

    constexpr size_t XE = (size_t)GM * GN;
    constexpr size_t WE = (size_t)GN * GK;
    constexpr size_t KVE = (size_t)64 * 128 * 64;

    __hip_bfloat16* xb  = (__hip_bfloat16*)d_ws;
    __hip_bfloat16* wqb = xb + XE;
    __hip_bfloat16* wkb = wqb + WE;
    __hip_bfloat16* wvb = wkb + WE;
    __hip_bfloat16* wob = wvb + WE;
    __hip_bfloat16* R1  = wob + WE;          // K, later O
    __hip_bfloat16* R2  = R1 + XE;           // V
    __hip_bfloat16* R3  = R2 + XE;           // Q (fused only)

    const size_t need_fused = ((4 * XE + 4 * WE) * 2 + KVE * 4 + 256);
    const bool fused = ws_size >= need_fused;

    float* gKV;
    int* flag;
    if (fused) {
        gKV = (float*)(R3 + XE);
        flag = (int*)(gKV + KVE);
    } else {
        gKV = (float*)(R2 + XE);
        flag = (int*)(gKV + KVE);
    }

    dim3 blk(256);
    hipLaunchKernelGGL(detect_kernel, dim3(1), dim3(64), 0, stream,
                       (const unsigned short*)x, flag);
    hipMemsetAsync(gKV, 0, KVE * sizeof(float), stream);

    hipLaunchKernelGGL(cvt_kernel, dim3(8192), blk, 0, stream, x,  xb,  (int)XE, flag);
    hipLaunchKernelGGL(cvt_kernel, dim3(512),  blk, 0, stream, Wq, wqb, (int)WE, flag);
    hipLaunchKernelGGL(cvt_kernel, dim3(512),  blk, 0, stream, Wk, wkb, (int)WE, flag);
    hipLaunchKernelGGL(cvt_kernel, dim3(512),  blk, 0, stream, Wv, wvb, (int)WE, flag);
    hipLaunchKernelGGL(cvt_kernel, dim3(512),  blk, 0, stream, Wo, wob, (int)WE, flag);

    if (fused) {
        hipLaunchKernelGGL(gemm_bias_kernel, dim3(3072), blk, 0, stream,
                           x, xb, Wk, Wv, Wq, wkb, wvb, wqb, bk, bv, bq,
                           R1, R2, R3, flag, 0);
        hipLaunchKernelGGL(kv_kernel, dim3(16, 64), blk, 0, stream, R1, R2, P, gKV, flag);
        hipLaunchKernelGGL(o_kernel, dim3(16, 64), blk, 0, stream, R3, P, gKV, R1, flag);
        hipLaunchKernelGGL(gemm_bias_kernel, dim3(1024), blk, 0, stream,
                           R1, R1, Wo, Wo, Wo, wob, wob, wob, bo, bo, bo,
                           d_out, d_out, d_out, flag, 1);
    } else {
        hipLaunchKernelGGL(gemm_bias_kernel, dim3(1024), blk, 0, stream,
                           x, xb, Wk, Wk, Wk, wkb, wkb, wkb, bk, bk, bk,
                           R1, R1, R1, flag, 0);
        hipLaunchKernelGGL(gemm_bias_kernel, dim3(1024), blk, 0, stream,
                           x, xb, Wv, Wv, Wv, wvb, wvb, wvb, bv, bv, bv,
                           R2, R2, R2, flag, 0);
        hipLaunchKernelGGL(kv_kernel, dim3(16, 64), blk, 0, stream, R1, R2, P, gKV, flag);
        hipLaunchKernelGGL(gemm_bias_kernel, dim3(1024), blk, 0, stream,
                           x, xb, Wq, Wq, Wq, wqb, wqb, wqb, bq, bq, bq,
                           R2, R2, R2, flag, 0);
        hipLaunchKernelGGL(o_kernel, dim3(16, 64), blk, 0, stream, R2, P, gKV, R1, flag);
        hipLaunchKernelGGL(gemm_bias_kernel, dim3(1024), blk, 0, stream,
                           R1, R1, Wo, Wo, Wo, wob, wob, wob, bo, bo, bo,
                           d_out, d_out, d_out, flag, 1);
    }
}

// Round 6
// 404.543 us; speedup vs baseline: 1.8169x; 1.0212x over previous
//
#include <hip/hip_runtime.h>
#include <hip/hip_bf16.h>
#include <stdint.h>

// ---------------------------------------------------------------------------
// RandomFeatureAttention: B=4, N=4096, E=1024, H=16, D=64, P_DIM=64, feat=128
// Round 6: 2-output KV GEMM (shared A-tile, 64 MFMA/barrier); kv/o rebuilt on
// wave-local LDS ownership (kv: 2 barriers/iter, o: 0 in-loop barriers).
// ---------------------------------------------------------------------------

typedef __bf16 bf16x8 __attribute__((ext_vector_type(8)));
typedef float f32x4 __attribute__((ext_vector_type(4)));

#define AS1 __attribute__((address_space(1)))
#define AS3 __attribute__((address_space(3)))

__device__ __forceinline__ void gl2lds16(const void* g, void* l) {
    __builtin_amdgcn_global_load_lds((const AS1 void*)g, (AS3 void*)l, 16, 0, 0);
}

static constexpr int GM = 16384, GN = 1024, GK = 1024;

// ----------------------------- dtype detect --------------------------------
__global__ void detect_kernel(const unsigned short* __restrict__ x,
                              int* __restrict__ flag) {
    __shared__ int s;
    const int lane = threadIdx.x;  // 64 threads
    if (lane == 0) s = 0;
    __syncthreads();
    int cnt = 0;
#pragma unroll
    for (int i = 0; i < 2; ++i) {
        const unsigned short u = x[i * 64 + lane];
        const int e = (u >> 7) & 0xFF;
        cnt += (e >= 117 && e <= 131) ? 1 : 0;
    }
    atomicAdd(&s, cnt);
    __syncthreads();
    if (lane == 0) *flag = (s >= 100) ? 1 : 0;  // 1 = bf16 storage
}

// ----------------------------- convert -------------------------------------
__global__ __launch_bounds__(256) void cvt_kernel(
    const void* __restrict__ src, __hip_bfloat16* __restrict__ dst,
    int n, const int* __restrict__ flag) {
    if (*flag) return;
    const int i = (blockIdx.x * 256 + threadIdx.x) * 8;
    if (i >= n) return;
    const float* s = (const float*)src + i;
    const float4 a = *(const float4*)s;
    const float4 b = *(const float4*)(s + 4);
    union { uint4 u; __hip_bfloat16 h[8]; } pk;
    pk.h[0] = __float2bfloat16(a.x); pk.h[1] = __float2bfloat16(a.y);
    pk.h[2] = __float2bfloat16(a.z); pk.h[3] = __float2bfloat16(a.w);
    pk.h[4] = __float2bfloat16(b.x); pk.h[5] = __float2bfloat16(b.y);
    pk.h[6] = __float2bfloat16(b.z); pk.h[7] = __float2bfloat16(b.w);
    *(uint4*)(dst + i) = pk.u;
}

// ------------------------- single-output GEMM ------------------------------
// C = A@W^T + bias. 128x128 tile, BK=64, 4 waves. Grid 1024, XCD-pinned.
__global__ __launch_bounds__(256) void gemm1_kernel(
    const void* __restrict__ Adirect,
    const __hip_bfloat16* __restrict__ Acvt,
    const void* __restrict__ Wr, const __hip_bfloat16* __restrict__ Wc,
    const void* __restrict__ bias_raw,
    void* __restrict__ Cout,
    const int* __restrict__ flag, int last)
{
    __shared__ unsigned short smem[2 * 128 * 64];
    unsigned short* sA = smem;
    unsigned short* sB = smem + 128 * 64;

    const int tid  = threadIdx.x;
    const int lane = tid & 63;
    const int w    = tid >> 6;
    const int wm   = w >> 1, wn = w & 1;
    const int lr   = lane & 15, lk = lane >> 4;

    const int id    = blockIdx.x;
    const int xcd   = id & 7;
    const int slot  = id >> 3;
    const int m0    = (xcd * 16 + (slot & 15)) * 128;
    const int n0    = (slot >> 4) * 128;
    const int fl    = *flag;

    const __hip_bfloat16* A = fl ? (const __hip_bfloat16*)Adirect : Acvt;
    const __hip_bfloat16* W = fl ? (const __hip_bfloat16*)Wr : Wc;

    f32x4 acc[4][4];
#pragma unroll
    for (int i = 0; i < 4; ++i)
#pragma unroll
        for (int j = 0; j < 4; ++j)
            acc[i][j] = (f32x4){0.f, 0.f, 0.f, 0.f};

    const __hip_bfloat16* Ab = A + (size_t)m0 * GK;
    const __hip_bfloat16* Wb = W + (size_t)n0 * GK;

    for (int k0 = 0; k0 < GK; k0 += 64) {
#pragma unroll
        for (int j = 0; j < 4; ++j) {
            const int chunk = j * 256 + tid;
            const int row   = chunk >> 3;
            const int c     = chunk & 7;
            const int cs    = c ^ (row & 7);
            gl2lds16(Ab + (size_t)row * GK + k0 + cs * 8,
                     (char*)sA + (j * 256 + w * 64) * 16);
            gl2lds16(Wb + (size_t)row * GK + k0 + cs * 8,
                     (char*)sB + (j * 256 + w * 64) * 16);
        }
        __syncthreads();
#pragma unroll
        for (int kk = 0; kk < 64; kk += 32) {
            const int jj = ((kk >> 3) + lk) ^ (lr & 7);
            bf16x8 af[4], bfr[4];
#pragma unroll
            for (int i = 0; i < 4; ++i)
                af[i] = *(const bf16x8*)&sA[(wm * 64 + i * 16 + lr) * 64 + jj * 8];
#pragma unroll
            for (int j = 0; j < 4; ++j)
                bfr[j] = *(const bf16x8*)&sB[(wn * 64 + j * 16 + lr) * 64 + jj * 8];
#pragma unroll
            for (int i = 0; i < 4; ++i)
#pragma unroll
                for (int j = 0; j < 4; ++j)
                    acc[i][j] = __builtin_amdgcn_mfma_f32_16x16x32_bf16(
                        af[i], bfr[j], acc[i][j], 0, 0, 0);
        }
        __syncthreads();
    }

    const bool f32out = (last != 0) && (fl == 0);
    if (f32out) {
#pragma unroll
        for (int j = 0; j < 4; ++j) {
            const int col = n0 + wn * 64 + j * 16 + lr;
            const float bv = ((const float*)bias_raw)[col];
#pragma unroll
            for (int i = 0; i < 4; ++i) {
                const int rbase = m0 + wm * 64 + i * 16 + lk * 4;
#pragma unroll
                for (int r = 0; r < 4; ++r)
                    ((float*)Cout)[(size_t)(rbase + r) * GN + col] = acc[i][j][r] + bv;
            }
        }
        return;
    }
    __hip_bfloat16* sC = (__hip_bfloat16*)smem;
#pragma unroll
    for (int j = 0; j < 4; ++j) {
        const int col = wn * 64 + j * 16 + lr;
        const float bv = fl ? __bfloat162float(((const __hip_bfloat16*)bias_raw)[n0 + col])
                            : ((const float*)bias_raw)[n0 + col];
        const int c2 = col >> 3, o = col & 7;
#pragma unroll
        for (int i = 0; i < 4; ++i) {
            const int rb = wm * 64 + i * 16 + lk * 4;
#pragma unroll
            for (int r = 0; r < 4; ++r) {
                const int row = rb + r;
                sC[row * 128 + (c2 ^ (row & 7)) * 8 + o] = __float2bfloat16(acc[i][j][r] + bv);
            }
        }
    }
    __syncthreads();
    {
        const int row = tid >> 1, hf = tid & 1;
        __hip_bfloat16* dst = (__hip_bfloat16*)Cout + (size_t)(m0 + row) * GN + n0 + hf * 64;
#pragma unroll
        for (int q = 0; q < 8; ++q) {
            const int cc = (hf * 8 + q) ^ (row & 7);
            *(uint4*)(dst + q * 8) = *(const uint4*)&sC[row * 128 + cc * 8];
        }
    }
}

// ------------------------- 2-output GEMM (K,V) -----------------------------
// Shares the A tile: per iter stage A,B0,B1; 64 MFMA per barrier pair.
__global__ __launch_bounds__(256, 2) void gemm2_kernel(
    const void* __restrict__ Adirect,
    const __hip_bfloat16* __restrict__ Acvt,
    const void* __restrict__ W0r, const __hip_bfloat16* __restrict__ W0c,
    const void* __restrict__ W1r, const __hip_bfloat16* __restrict__ W1c,
    const void* __restrict__ b0r, const void* __restrict__ b1r,
    void* __restrict__ o0, void* __restrict__ o1,
    const int* __restrict__ flag)
{
    __shared__ unsigned short smem[3 * 128 * 64];  // sA | sB0 | sB1 ; C-repack reuses
    unsigned short* sA  = smem;
    unsigned short* sB0 = smem + 128 * 64;
    unsigned short* sB1 = smem + 2 * 128 * 64;

    const int tid  = threadIdx.x;
    const int lane = tid & 63;
    const int w    = tid >> 6;
    const int wm   = w >> 1, wn = w & 1;
    const int lr   = lane & 15, lk = lane >> 4;

    const int id    = blockIdx.x;
    const int xcd   = id & 7;
    const int slot  = id >> 3;
    const int m0    = (xcd * 16 + (slot & 15)) * 128;
    const int n0    = (slot >> 4) * 128;
    const int fl    = *flag;

    const __hip_bfloat16* A  = fl ? (const __hip_bfloat16*)Adirect : Acvt;
    const __hip_bfloat16* W0 = fl ? (const __hip_bfloat16*)W0r : W0c;
    const __hip_bfloat16* W1 = fl ? (const __hip_bfloat16*)W1r : W1c;

    f32x4 acc[2][4][4];
#pragma unroll
    for (int t = 0; t < 2; ++t)
#pragma unroll
        for (int i = 0; i < 4; ++i)
#pragma unroll
            for (int j = 0; j < 4; ++j)
                acc[t][i][j] = (f32x4){0.f, 0.f, 0.f, 0.f};

    const __hip_bfloat16* Ab  = A + (size_t)m0 * GK;
    const __hip_bfloat16* W0b = W0 + (size_t)n0 * GK;
    const __hip_bfloat16* W1b = W1 + (size_t)n0 * GK;

    for (int k0 = 0; k0 < GK; k0 += 64) {
#pragma unroll
        for (int j = 0; j < 4; ++j) {
            const int chunk = j * 256 + tid;
            const int row   = chunk >> 3;
            const int c     = chunk & 7;
            const int cs    = c ^ (row & 7);
            const size_t go = (size_t)row * GK + k0 + cs * 8;
            const int lo = (j * 256 + w * 64) * 16;
            gl2lds16(Ab  + go, (char*)sA  + lo);
            gl2lds16(W0b + go, (char*)sB0 + lo);
            gl2lds16(W1b + go, (char*)sB1 + lo);
        }
        __syncthreads();
#pragma unroll
        for (int kk = 0; kk < 64; kk += 32) {
            const int jj = ((kk >> 3) + lk) ^ (lr & 7);
            bf16x8 af[4], b0f[4], b1f[4];
#pragma unroll
            for (int i = 0; i < 4; ++i)
                af[i] = *(const bf16x8*)&sA[(wm * 64 + i * 16 + lr) * 64 + jj * 8];
#pragma unroll
            for (int j = 0; j < 4; ++j)
                b0f[j] = *(const bf16x8*)&sB0[(wn * 64 + j * 16 + lr) * 64 + jj * 8];
#pragma unroll
            for (int j = 0; j < 4; ++j)
                b1f[j] = *(const bf16x8*)&sB1[(wn * 64 + j * 16 + lr) * 64 + jj * 8];
#pragma unroll
            for (int i = 0; i < 4; ++i)
#pragma unroll
                for (int j = 0; j < 4; ++j) {
                    acc[0][i][j] = __builtin_amdgcn_mfma_f32_16x16x32_bf16(
                        af[i], b0f[j], acc[0][i][j], 0, 0, 0);
                    acc[1][i][j] = __builtin_amdgcn_mfma_f32_16x16x32_bf16(
                        af[i], b1f[j], acc[1][i][j], 0, 0, 0);
                }
        }
        __syncthreads();
    }

    // epilogue per output: repack through LDS, vectorized stores
    __hip_bfloat16* sC = (__hip_bfloat16*)smem;
#pragma unroll
    for (int t = 0; t < 2; ++t) {
        const void* bias_raw = t ? b1r : b0r;
        void* Cout = t ? o1 : o0;
#pragma unroll
        for (int j = 0; j < 4; ++j) {
            const int col = wn * 64 + j * 16 + lr;
            const float bv = fl ? __bfloat162float(((const __hip_bfloat16*)bias_raw)[n0 + col])
                                : ((const float*)bias_raw)[n0 + col];
            const int c2 = col >> 3, o = col & 7;
#pragma unroll
            for (int i = 0; i < 4; ++i) {
                const int rb = wm * 64 + i * 16 + lk * 4;
#pragma unroll
                for (int r = 0; r < 4; ++r) {
                    const int row = rb + r;
                    sC[row * 128 + (c2 ^ (row & 7)) * 8 + o] =
                        __float2bfloat16(acc[t][i][j][r] + bv);
                }
            }
        }
        __syncthreads();
        {
            const int row = tid >> 1, hf = tid & 1;
            __hip_bfloat16* dst = (__hip_bfloat16*)Cout + (size_t)(m0 + row) * GN + n0 + hf * 64;
#pragma unroll
            for (int q = 0; q < 8; ++q) {
                const int cc = (hf * 8 + q) ^ (row & 7);
                *(uint4*)(dst + q * 8) = *(const uint4*)&sC[row * 128 + cc * 8];
            }
        }
        __syncthreads();
    }
}

// ----------------------------- shared helpers -------------------------------
__device__ __forceinline__ void load_P(const void* Praw, int f,
                                       __hip_bfloat16* sP, int tid) {
    const int e = tid >> 2, q = tid & 3;
    union { uint4 u[2]; __hip_bfloat16 h[16]; } pk;
    if (f) {
        pk.u[0] = *(const uint4*)((const __hip_bfloat16*)Praw + e * 64 + q * 16);
        pk.u[1] = *(const uint4*)((const __hip_bfloat16*)Praw + e * 64 + q * 16 + 8);
    } else {
        const float* ps = (const float*)Praw + e * 64 + q * 16;
#pragma unroll
        for (int j = 0; j < 16; ++j) pk.h[j] = __float2bfloat16(ps[j]);
    }
    *(uint4*)&sP[e * 72 + q * 16]     = pk.u[0];
    *(uint4*)&sP[e * 72 + q * 16 + 8] = pk.u[1];
}

__device__ __forceinline__ float sumsq16(uint4 a, uint4 b) {
    union { uint4 u; __hip_bfloat16 h[8]; } x0, x1;
    x0.u = a; x1.u = b;
    float ss = 0.f;
#pragma unroll
    for (int j = 0; j < 8; ++j) {
        float v0 = __bfloat162float(x0.h[j]); ss += v0 * v0;
        float v1 = __bfloat162float(x1.h[j]); ss += v1 * v1;
    }
    return ss;
}

// ----------------------------- kv kernel -----------------------------------
// grid (16, 64). Wave-local ownership: wave w owns tokens 16w..16w+15 in
// sK/sRN/sKFT-columns; only sVT/sKFT consumption is cross-wave -> 2 barriers.
__global__ __launch_bounds__(256) void kv_kernel(
    const __hip_bfloat16* __restrict__ Km,
    const __hip_bfloat16* __restrict__ Vm,
    const void* __restrict__ Praw,
    float* __restrict__ gKV,
    const int* __restrict__ flag)
{
    __shared__ __hip_bfloat16 sK[64 * 72];     // [n][d] (wave-local rows)
    __shared__ __hip_bfloat16 sVT[64 * 72];    // [d][n] (cross-wave)
    __shared__ __hip_bfloat16 sP[64 * 72];     // [e][d] (read-only)
    __shared__ __hip_bfloat16 sKFT[128 * 72];  // [e][n] (cross-wave)
    __shared__ float sRN[64];

    const int tid  = threadIdx.x;
    const int lane = tid & 63;
    const int w    = tid >> 6;
    const int lr   = lane & 15, lk = lane >> 4;
    const int bh   = blockIdx.y;
    const int b    = bh >> 4, h = bh & 15;
    const int nst  = blockIdx.x * 256;
    const int f    = *flag;
    const int n    = tid >> 2, q2 = tid & 3;

    load_P(Praw, f, sP, tid);

    f32x4 acck[2][4];
#pragma unroll
    for (int i = 0; i < 2; ++i)
#pragma unroll
        for (int j = 0; j < 4; ++j)
            acck[i][j] = (f32x4){0.f, 0.f, 0.f, 0.f};

    size_t base = ((size_t)(b * 4096 + nst + n)) * 1024 + h * 64 + q2 * 16;
    uint4 ka = *(const uint4*)(Km + base), kb = *(const uint4*)(Km + base + 8);
    uint4 va = *(const uint4*)(Vm + base), vb = *(const uint4*)(Vm + base + 8);

    for (int s = 0; s < 4; ++s) {
        __syncthreads();  // prev kv-MFMA done with sVT/sKFT (s==0: sP visible)
        *(uint4*)&sK[n * 72 + q2 * 16]     = ka;
        *(uint4*)&sK[n * 72 + q2 * 16 + 8] = kb;
        {
            union { uint4 u[2]; __hip_bfloat16 h[16]; } vv;
            vv.u[0] = va; vv.u[1] = vb;
#pragma unroll
            for (int j = 0; j < 16; ++j) sVT[(q2 * 16 + j) * 72 + n] = vv.h[j];
        }
        {
            float ss = sumsq16(ka, kb);
            ss += __shfl_xor(ss, 1, 64);
            ss += __shfl_xor(ss, 2, 64);
            if (q2 == 0) sRN[n] = 2.0f / (sqrtf(ss) + 1e-4f);  // H^0.25 = 2
        }
        if (s < 3) {
            base = ((size_t)(b * 4096 + nst + (s + 1) * 64 + n)) * 1024 + h * 64 + q2 * 16;
            ka = *(const uint4*)(Km + base); kb = *(const uint4*)(Km + base + 8);
            va = *(const uint4*)(Vm + base); vb = *(const uint4*)(Vm + base + 8);
        }
        // proj: wave-local sK rows + sRN -> sKFT token-columns (no barrier)
        {
            bf16x8 afr0 = *(const bf16x8*)&sK[(w * 16 + lr) * 72 + lk * 8];
            bf16x8 afr1 = *(const bf16x8*)&sK[(w * 16 + lr) * 72 + 32 + lk * 8];
            float rn[4];
#pragma unroll
            for (int r = 0; r < 4; ++r) rn[r] = sRN[w * 16 + lk * 4 + r];
#pragma unroll
            for (int eb = 0; eb < 4; ++eb) {
                f32x4 pa = (f32x4){0.f, 0.f, 0.f, 0.f};
                bf16x8 b0 = *(const bf16x8*)&sP[(eb * 16 + lr) * 72 + lk * 8];
                bf16x8 b1 = *(const bf16x8*)&sP[(eb * 16 + lr) * 72 + 32 + lk * 8];
                pa = __builtin_amdgcn_mfma_f32_16x16x32_bf16(afr0, b0, pa, 0, 0, 0);
                pa = __builtin_amdgcn_mfma_f32_16x16x32_bf16(afr1, b1, pa, 0, 0, 0);
                const int col = eb * 16 + lr;
#pragma unroll
                for (int r = 0; r < 4; ++r) {
                    const int row = w * 16 + lk * 4 + r;
                    float sv, cv;
                    __sincosf(pa[r] * rn[r], &sv, &cv);
                    sKFT[col * 72 + row]        = __float2bfloat16(sv * 0.125f);
                    sKFT[(col + 64) * 72 + row] = __float2bfloat16(cv * 0.125f);
                }
            }
        }
        __syncthreads();  // sKFT + sVT complete across waves
#pragma unroll
        for (int ks = 0; ks < 2; ++ks) {
            bf16x8 a2[2], b2[4];
            a2[0] = *(const bf16x8*)&sKFT[(w * 16 + lr) * 72 + ks * 32 + lk * 8];
            a2[1] = *(const bf16x8*)&sKFT[((w + 4) * 16 + lr) * 72 + ks * 32 + lk * 8];
#pragma unroll
            for (int db = 0; db < 4; ++db)
                b2[db] = *(const bf16x8*)&sVT[(db * 16 + lr) * 72 + ks * 32 + lk * 8];
#pragma unroll
            for (int i = 0; i < 2; ++i)
#pragma unroll
                for (int db = 0; db < 4; ++db)
                    acck[i][db] = __builtin_amdgcn_mfma_f32_16x16x32_bf16(
                        a2[i], b2[db], acck[i][db], 0, 0, 0);
        }
    }

    float* out = gKV + (size_t)bh * 8192;
#pragma unroll
    for (int i = 0; i < 2; ++i)
#pragma unroll
        for (int db = 0; db < 4; ++db)
#pragma unroll
            for (int r = 0; r < 4; ++r) {
                const int e = (w + 4 * i) * 16 + lk * 4 + r;
                const int d = db * 16 + lr;
                atomicAdd(out + e * 64 + d, acck[i][db][r]);
            }
}

// ----------------------------- o kernel ------------------------------------
// grid (16, 64). Fully wave-local per iter -> no in-loop barriers.
__global__ __launch_bounds__(256) void o_kernel(
    const __hip_bfloat16* __restrict__ Qm,
    const void* __restrict__ Praw,
    const float* __restrict__ gKV,
    __hip_bfloat16* __restrict__ O,
    const int* __restrict__ flag)
{
    __shared__ __hip_bfloat16 sQ[64 * 72];     // [n][d] wave-local rows
    __shared__ __hip_bfloat16 sP[64 * 72];     // read-only
    __shared__ __hip_bfloat16 sQF[64 * 136];   // [n][e] wave-local rows
    __shared__ __hip_bfloat16 sKVT[64 * 136];  // [d][e] read-only
    __shared__ float sRN[64];

    const int tid  = threadIdx.x;
    const int lane = tid & 63;
    const int w    = tid >> 6;
    const int lr   = lane & 15, lk = lane >> 4;
    const int bh   = blockIdx.y;
    const int b    = bh >> 4, h = bh & 15;
    const int nst  = blockIdx.x * 256;
    const int f    = *flag;
    const int n    = tid >> 2, q2 = tid & 3;

    load_P(Praw, f, sP, tid);
    {
        const float* kvsrc = gKV + (size_t)bh * 8192;
        for (int t = tid; t < 8192; t += 256) {
            const int e = t >> 6, d = t & 63;
            sKVT[d * 136 + e] = __float2bfloat16(kvsrc[t]);
        }
    }

    size_t base = ((size_t)(b * 4096 + nst + n)) * 1024 + h * 64 + q2 * 16;
    uint4 qa = *(const uint4*)(Qm + base), qb = *(const uint4*)(Qm + base + 8);

    __syncthreads();  // sP + sKVT visible to all waves

    for (int s = 0; s < 4; ++s) {
        const int gn0 = nst + s * 64;
        *(uint4*)&sQ[n * 72 + q2 * 16]     = qa;
        *(uint4*)&sQ[n * 72 + q2 * 16 + 8] = qb;
        {
            float ss = sumsq16(qa, qb);
            ss += __shfl_xor(ss, 1, 64);
            ss += __shfl_xor(ss, 2, 64);
            if (q2 == 0) sRN[n] = 2.0f / (sqrtf(ss) + 1e-4f);
        }
        if (s < 3) {
            base = ((size_t)(b * 4096 + nst + (s + 1) * 64 + n)) * 1024 + h * 64 + q2 * 16;
            qa = *(const uint4*)(Qm + base); qb = *(const uint4*)(Qm + base + 8);
        }
        {
            bf16x8 afr0 = *(const bf16x8*)&sQ[(w * 16 + lr) * 72 + lk * 8];
            bf16x8 afr1 = *(const bf16x8*)&sQ[(w * 16 + lr) * 72 + 32 + lk * 8];
            float rn[4];
#pragma unroll
            for (int r = 0; r < 4; ++r) rn[r] = sRN[w * 16 + lk * 4 + r];
#pragma unroll
            for (int eb = 0; eb < 4; ++eb) {
                f32x4 pa = (f32x4){0.f, 0.f, 0.f, 0.f};
                bf16x8 b0 = *(const bf16x8*)&sP[(eb * 16 + lr) * 72 + lk * 8];
                bf16x8 b1 = *(const bf16x8*)&sP[(eb * 16 + lr) * 72 + 32 + lk * 8];
                pa = __builtin_amdgcn_mfma_f32_16x16x32_bf16(afr0, b0, pa, 0, 0, 0);
                pa = __builtin_amdgcn_mfma_f32_16x16x32_bf16(afr1, b1, pa, 0, 0, 0);
                const int col = eb * 16 + lr;
#pragma unroll
                for (int r = 0; r < 4; ++r) {
                    const int row = w * 16 + lk * 4 + r;
                    float sv, cv;
                    __sincosf(pa[r] * rn[r], &sv, &cv);
                    sQF[row * 136 + col]      = __float2bfloat16(sv * 0.125f);
                    sQF[row * 136 + 64 + col] = __float2bfloat16(cv * 0.125f);
                }
            }
        }
        f32x4 oacc[4];
#pragma unroll
        for (int nb = 0; nb < 4; ++nb) oacc[nb] = (f32x4){0.f, 0.f, 0.f, 0.f};
#pragma unroll
        for (int ks = 0; ks < 4; ++ks) {
            bf16x8 aa = *(const bf16x8*)&sQF[(w * 16 + lr) * 136 + ks * 32 + lk * 8];
#pragma unroll
            for (int nb = 0; nb < 4; ++nb) {
                bf16x8 bb = *(const bf16x8*)&sKVT[(nb * 16 + lr) * 136 + ks * 32 + lk * 8];
                oacc[nb] = __builtin_amdgcn_mfma_f32_16x16x32_bf16(aa, bb, oacc[nb], 0, 0, 0);
            }
        }
#pragma unroll
        for (int nb = 0; nb < 4; ++nb)
#pragma unroll
            for (int r = 0; r < 4; ++r)
                sQ[(w * 16 + lk * 4 + r) * 72 + nb * 16 + lr] =
                    __float2bfloat16(oacc[nb][r]);
        {
            uint4 o0 = *(uint4*)&sQ[n * 72 + q2 * 16];
            uint4 o1 = *(uint4*)&sQ[n * 72 + q2 * 16 + 8];
            const size_t obase = ((size_t)(b * 4096 + gn0 + n)) * 1024 + h * 64 + q2 * 16;
            *(uint4*)(O + obase)     = o0;
            *(uint4*)(O + obase + 8) = o1;
        }
    }
}

// ----------------------------- launcher ------------------------------------
extern "C" void kernel_launch(void* const* d_in, const int* in_sizes, int n_in,
                              void* d_out, int out_size, void* d_ws, size_t ws_size,
                              hipStream_t stream)
{
    (void)in_sizes; (void)n_in; (void)out_size; (void)ws_size;
    const void* x  = d_in[0];
    const void* Wq = d_in[1];
    const void* bq = d_in[2];
    const void* Wk = d_in[3];
    const void* bk = d_in[4];
    const void* Wv = d_in[5];
    const void* bv = d_in[6];
    const void* Wo = d_in[7];
    const void* bo = d_in[8];
    const void* P  = d_in[9];

    constexpr size_t XE = (size_t)GM * GN;
    constexpr size_t WE = (size_t)GN * GK;
    constexpr size_t KVE = (size_t)64 * 128 * 64;

    __hip_bfloat16* xb  = (__hip_bfloat16*)d_ws;
    __hip_bfloat16* wqb = xb + XE;
    __hip_bfloat16* wkb = wqb + WE;
    __hip_bfloat16* wvb = wkb + WE;
    __hip_bfloat16* wob = wvb + WE;
    __hip_bfloat16* R1  = wob + WE;          // K, later O
    __hip_bfloat16* R2  = R1 + XE;           // V, later Q
    float* gKV = (float*)(R2 + XE);
    int* flag  = (int*)(gKV + KVE);

    dim3 blk(256);
    hipLaunchKernelGGL(detect_kernel, dim3(1), dim3(64), 0, stream,
                       (const unsigned short*)x, flag);
    hipMemsetAsync(gKV, 0, KVE * sizeof(float), stream);

    hipLaunchKernelGGL(cvt_kernel, dim3(8192), blk, 0, stream, x,  xb,  (int)XE, flag);
    hipLaunchKernelGGL(cvt_kernel, dim3(512),  blk, 0, stream, Wq, wqb, (int)WE, flag);
    hipLaunchKernelGGL(cvt_kernel, dim3(512),  blk, 0, stream, Wk, wkb, (int)WE, flag);
    hipLaunchKernelGGL(cvt_kernel, dim3(512),  blk, 0, stream, Wv, wvb, (int)WE, flag);
    hipLaunchKernelGGL(cvt_kernel, dim3(512),  blk, 0, stream, Wo, wob, (int)WE, flag);

    // K,V (2-out, shared A)
    hipLaunchKernelGGL(gemm2_kernel, dim3(1024), blk, 0, stream,
                       x, xb, Wk, wkb, Wv, wvb, bk, bv, R1, R2, flag);
    hipLaunchKernelGGL(kv_kernel, dim3(16, 64), blk, 0, stream, R1, R2, P, gKV, flag);
    // Q (V dead -> R2)
    hipLaunchKernelGGL(gemm1_kernel, dim3(1024), blk, 0, stream,
                       x, xb, Wq, wqb, bq, R2, flag, 0);
    hipLaunchKernelGGL(o_kernel, dim3(16, 64), blk, 0, stream, R2, P, gKV, R1, flag);
    // out = O@Wo^T + bo
    hipLaunchKernelGGL(gemm1_kernel, dim3(1024), blk, 0, stream,
                       R1, R1, Wo, wob, bo, d_out, flag, 1);
}

// Round 7
// 362.461 us; speedup vs baseline: 2.0279x; 1.1161x over previous
//
#include <hip/hip_runtime.h>
#include <hip/hip_bf16.h>
#include <stdint.h>

// ---------------------------------------------------------------------------
// RandomFeatureAttention: B=4, N=4096, E=1024, H=16, D=64, P_DIM=64, feat=128
// Round 7: dual-M gemm1 (shared W tile, 64 MFMA/barrier) for Q & final;
// kv atomics replaced by per-block partial slabs + reduce kernel.
// ---------------------------------------------------------------------------

typedef __bf16 bf16x8 __attribute__((ext_vector_type(8)));
typedef float f32x4 __attribute__((ext_vector_type(4)));

#define AS1 __attribute__((address_space(1)))
#define AS3 __attribute__((address_space(3)))

__device__ __forceinline__ void gl2lds16(const void* g, void* l) {
    __builtin_amdgcn_global_load_lds((const AS1 void*)g, (AS3 void*)l, 16, 0, 0);
}

static constexpr int GM = 16384, GN = 1024, GK = 1024;
static constexpr int KV_SLABS = 8;

// ----------------------------- dtype detect --------------------------------
__global__ void detect_kernel(const unsigned short* __restrict__ x,
                              int* __restrict__ flag) {
    __shared__ int s;
    const int lane = threadIdx.x;  // 64 threads
    if (lane == 0) s = 0;
    __syncthreads();
    int cnt = 0;
#pragma unroll
    for (int i = 0; i < 2; ++i) {
        const unsigned short u = x[i * 64 + lane];
        const int e = (u >> 7) & 0xFF;
        cnt += (e >= 117 && e <= 131) ? 1 : 0;
    }
    atomicAdd(&s, cnt);
    __syncthreads();
    if (lane == 0) *flag = (s >= 100) ? 1 : 0;  // 1 = bf16 storage
}

// ----------------------------- convert -------------------------------------
__global__ __launch_bounds__(256) void cvt_kernel(
    const void* __restrict__ src, __hip_bfloat16* __restrict__ dst,
    int n, const int* __restrict__ flag) {
    if (*flag) return;
    const int i = (blockIdx.x * 256 + threadIdx.x) * 8;
    if (i >= n) return;
    const float* s = (const float*)src + i;
    const float4 a = *(const float4*)s;
    const float4 b = *(const float4*)(s + 4);
    union { uint4 u; __hip_bfloat16 h[8]; } pk;
    pk.h[0] = __float2bfloat16(a.x); pk.h[1] = __float2bfloat16(a.y);
    pk.h[2] = __float2bfloat16(a.z); pk.h[3] = __float2bfloat16(a.w);
    pk.h[4] = __float2bfloat16(b.x); pk.h[5] = __float2bfloat16(b.y);
    pk.h[6] = __float2bfloat16(b.z); pk.h[7] = __float2bfloat16(b.w);
    *(uint4*)(dst + i) = pk.u;
}

// --------------------- dual-M single-W GEMM (Q, final) ---------------------
// Block computes 256x128 (two 128x128 M-tiles sharing the W tile).
// Grid 512, XCD-pinned: xcd owns mpairs [xcd*8, xcd*8+8) (A slab 4MB = L2).
__global__ __launch_bounds__(256, 2) void gemm1m2_kernel(
    const void* __restrict__ Adirect,
    const __hip_bfloat16* __restrict__ Acvt,
    const void* __restrict__ Wr, const __hip_bfloat16* __restrict__ Wc,
    const void* __restrict__ bias_raw,
    void* __restrict__ Cout,
    const int* __restrict__ flag, int last)
{
    __shared__ unsigned short smem[3 * 128 * 64];  // sA0 | sA1 | sB
    unsigned short* sA0 = smem;
    unsigned short* sA1 = smem + 128 * 64;
    unsigned short* sB  = smem + 2 * 128 * 64;

    const int tid  = threadIdx.x;
    const int lane = tid & 63;
    const int w    = tid >> 6;
    const int wm   = w >> 1, wn = w & 1;
    const int lr   = lane & 15, lk = lane >> 4;

    const int id   = blockIdx.x;
    const int xcd  = id & 7;
    const int s    = id >> 3;
    const int m0   = (xcd * 8 + (s & 7)) * 256;
    const int n0   = (s >> 3) * 128;
    const int fl   = *flag;

    const __hip_bfloat16* A = fl ? (const __hip_bfloat16*)Adirect : Acvt;
    const __hip_bfloat16* W = fl ? (const __hip_bfloat16*)Wr : Wc;

    f32x4 acc[2][4][4];
#pragma unroll
    for (int t = 0; t < 2; ++t)
#pragma unroll
        for (int i = 0; i < 4; ++i)
#pragma unroll
            for (int j = 0; j < 4; ++j)
                acc[t][i][j] = (f32x4){0.f, 0.f, 0.f, 0.f};

    const __hip_bfloat16* Ab0 = A + (size_t)m0 * GK;
    const __hip_bfloat16* Ab1 = A + (size_t)(m0 + 128) * GK;
    const __hip_bfloat16* Wb  = W + (size_t)n0 * GK;

    for (int k0 = 0; k0 < GK; k0 += 64) {
#pragma unroll
        for (int j = 0; j < 4; ++j) {
            const int chunk = j * 256 + tid;
            const int row   = chunk >> 3;
            const int c     = chunk & 7;
            const int cs    = c ^ (row & 7);
            const size_t go = (size_t)row * GK + k0 + cs * 8;
            const int lo = (j * 256 + w * 64) * 16;
            gl2lds16(Ab0 + go, (char*)sA0 + lo);
            gl2lds16(Ab1 + go, (char*)sA1 + lo);
            gl2lds16(Wb  + go, (char*)sB  + lo);
        }
        __syncthreads();
#pragma unroll
        for (int kk = 0; kk < 64; kk += 32) {
            const int jj = ((kk >> 3) + lk) ^ (lr & 7);
            bf16x8 a0f[4], a1f[4], bfr[4];
#pragma unroll
            for (int i = 0; i < 4; ++i)
                a0f[i] = *(const bf16x8*)&sA0[(wm * 64 + i * 16 + lr) * 64 + jj * 8];
#pragma unroll
            for (int i = 0; i < 4; ++i)
                a1f[i] = *(const bf16x8*)&sA1[(wm * 64 + i * 16 + lr) * 64 + jj * 8];
#pragma unroll
            for (int j = 0; j < 4; ++j)
                bfr[j] = *(const bf16x8*)&sB[(wn * 64 + j * 16 + lr) * 64 + jj * 8];
#pragma unroll
            for (int i = 0; i < 4; ++i)
#pragma unroll
                for (int j = 0; j < 4; ++j) {
                    acc[0][i][j] = __builtin_amdgcn_mfma_f32_16x16x32_bf16(
                        a0f[i], bfr[j], acc[0][i][j], 0, 0, 0);
                    acc[1][i][j] = __builtin_amdgcn_mfma_f32_16x16x32_bf16(
                        a1f[i], bfr[j], acc[1][i][j], 0, 0, 0);
                }
        }
        __syncthreads();
    }

    const bool f32out = (last != 0) && (fl == 0);
    if (f32out) {
#pragma unroll
        for (int t = 0; t < 2; ++t)
#pragma unroll
            for (int j = 0; j < 4; ++j) {
                const int col = n0 + wn * 64 + j * 16 + lr;
                const float bv = ((const float*)bias_raw)[col];
#pragma unroll
                for (int i = 0; i < 4; ++i) {
                    const int rbase = m0 + t * 128 + wm * 64 + i * 16 + lk * 4;
#pragma unroll
                    for (int r = 0; r < 4; ++r)
                        ((float*)Cout)[(size_t)(rbase + r) * GN + col] = acc[t][i][j][r] + bv;
                }
            }
        return;
    }
    __hip_bfloat16* sC = (__hip_bfloat16*)smem;
#pragma unroll
    for (int t = 0; t < 2; ++t) {
#pragma unroll
        for (int j = 0; j < 4; ++j) {
            const int col = wn * 64 + j * 16 + lr;
            const float bv = fl ? __bfloat162float(((const __hip_bfloat16*)bias_raw)[n0 + col])
                                : ((const float*)bias_raw)[n0 + col];
            const int c2 = col >> 3, o = col & 7;
#pragma unroll
            for (int i = 0; i < 4; ++i) {
                const int rb = wm * 64 + i * 16 + lk * 4;
#pragma unroll
                for (int r = 0; r < 4; ++r) {
                    const int row = rb + r;
                    sC[row * 128 + (c2 ^ (row & 7)) * 8 + o] =
                        __float2bfloat16(acc[t][i][j][r] + bv);
                }
            }
        }
        __syncthreads();
        {
            const int row = tid >> 1, hf = tid & 1;
            __hip_bfloat16* dst = (__hip_bfloat16*)Cout +
                (size_t)(m0 + t * 128 + row) * GN + n0 + hf * 64;
#pragma unroll
            for (int q = 0; q < 8; ++q) {
                const int cc = (hf * 8 + q) ^ (row & 7);
                *(uint4*)(dst + q * 8) = *(const uint4*)&sC[row * 128 + cc * 8];
            }
        }
        __syncthreads();
    }
}

// ------------------------- 2-output GEMM (K,V) -----------------------------
__global__ __launch_bounds__(256, 2) void gemm2_kernel(
    const void* __restrict__ Adirect,
    const __hip_bfloat16* __restrict__ Acvt,
    const void* __restrict__ W0r, const __hip_bfloat16* __restrict__ W0c,
    const void* __restrict__ W1r, const __hip_bfloat16* __restrict__ W1c,
    const void* __restrict__ b0r, const void* __restrict__ b1r,
    void* __restrict__ o0, void* __restrict__ o1,
    const int* __restrict__ flag)
{
    __shared__ unsigned short smem[3 * 128 * 64];  // sA | sB0 | sB1
    unsigned short* sA  = smem;
    unsigned short* sB0 = smem + 128 * 64;
    unsigned short* sB1 = smem + 2 * 128 * 64;

    const int tid  = threadIdx.x;
    const int lane = tid & 63;
    const int w    = tid >> 6;
    const int wm   = w >> 1, wn = w & 1;
    const int lr   = lane & 15, lk = lane >> 4;

    const int id    = blockIdx.x;
    const int xcd   = id & 7;
    const int slot  = id >> 3;
    const int m0    = (xcd * 16 + (slot & 15)) * 128;
    const int n0    = (slot >> 4) * 128;
    const int fl    = *flag;

    const __hip_bfloat16* A  = fl ? (const __hip_bfloat16*)Adirect : Acvt;
    const __hip_bfloat16* W0 = fl ? (const __hip_bfloat16*)W0r : W0c;
    const __hip_bfloat16* W1 = fl ? (const __hip_bfloat16*)W1r : W1c;

    f32x4 acc[2][4][4];
#pragma unroll
    for (int t = 0; t < 2; ++t)
#pragma unroll
        for (int i = 0; i < 4; ++i)
#pragma unroll
            for (int j = 0; j < 4; ++j)
                acc[t][i][j] = (f32x4){0.f, 0.f, 0.f, 0.f};

    const __hip_bfloat16* Ab  = A + (size_t)m0 * GK;
    const __hip_bfloat16* W0b = W0 + (size_t)n0 * GK;
    const __hip_bfloat16* W1b = W1 + (size_t)n0 * GK;

    for (int k0 = 0; k0 < GK; k0 += 64) {
#pragma unroll
        for (int j = 0; j < 4; ++j) {
            const int chunk = j * 256 + tid;
            const int row   = chunk >> 3;
            const int c     = chunk & 7;
            const int cs    = c ^ (row & 7);
            const size_t go = (size_t)row * GK + k0 + cs * 8;
            const int lo = (j * 256 + w * 64) * 16;
            gl2lds16(Ab  + go, (char*)sA  + lo);
            gl2lds16(W0b + go, (char*)sB0 + lo);
            gl2lds16(W1b + go, (char*)sB1 + lo);
        }
        __syncthreads();
#pragma unroll
        for (int kk = 0; kk < 64; kk += 32) {
            const int jj = ((kk >> 3) + lk) ^ (lr & 7);
            bf16x8 af[4], b0f[4], b1f[4];
#pragma unroll
            for (int i = 0; i < 4; ++i)
                af[i] = *(const bf16x8*)&sA[(wm * 64 + i * 16 + lr) * 64 + jj * 8];
#pragma unroll
            for (int j = 0; j < 4; ++j)
                b0f[j] = *(const bf16x8*)&sB0[(wn * 64 + j * 16 + lr) * 64 + jj * 8];
#pragma unroll
            for (int j = 0; j < 4; ++j)
                b1f[j] = *(const bf16x8*)&sB1[(wn * 64 + j * 16 + lr) * 64 + jj * 8];
#pragma unroll
            for (int i = 0; i < 4; ++i)
#pragma unroll
                for (int j = 0; j < 4; ++j) {
                    acc[0][i][j] = __builtin_amdgcn_mfma_f32_16x16x32_bf16(
                        af[i], b0f[j], acc[0][i][j], 0, 0, 0);
                    acc[1][i][j] = __builtin_amdgcn_mfma_f32_16x16x32_bf16(
                        af[i], b1f[j], acc[1][i][j], 0, 0, 0);
                }
        }
        __syncthreads();
    }

    __hip_bfloat16* sC = (__hip_bfloat16*)smem;
#pragma unroll
    for (int t = 0; t < 2; ++t) {
        const void* bias_raw = t ? b1r : b0r;
        void* Cout = t ? o1 : o0;
#pragma unroll
        for (int j = 0; j < 4; ++j) {
            const int col = wn * 64 + j * 16 + lr;
            const float bv = fl ? __bfloat162float(((const __hip_bfloat16*)bias_raw)[n0 + col])
                                : ((const float*)bias_raw)[n0 + col];
            const int c2 = col >> 3, o = col & 7;
#pragma unroll
            for (int i = 0; i < 4; ++i) {
                const int rb = wm * 64 + i * 16 + lk * 4;
#pragma unroll
                for (int r = 0; r < 4; ++r) {
                    const int row = rb + r;
                    sC[row * 128 + (c2 ^ (row & 7)) * 8 + o] =
                        __float2bfloat16(acc[t][i][j][r] + bv);
                }
            }
        }
        __syncthreads();
        {
            const int row = tid >> 1, hf = tid & 1;
            __hip_bfloat16* dst = (__hip_bfloat16*)Cout + (size_t)(m0 + row) * GN + n0 + hf * 64;
#pragma unroll
            for (int q = 0; q < 8; ++q) {
                const int cc = (hf * 8 + q) ^ (row & 7);
                *(uint4*)(dst + q * 8) = *(const uint4*)&sC[row * 128 + cc * 8];
            }
        }
        __syncthreads();
    }
}

// ----------------------------- shared helpers -------------------------------
__device__ __forceinline__ void load_P(const void* Praw, int f,
                                       __hip_bfloat16* sP, int tid) {
    const int e = tid >> 2, q = tid & 3;
    union { uint4 u[2]; __hip_bfloat16 h[16]; } pk;
    if (f) {
        pk.u[0] = *(const uint4*)((const __hip_bfloat16*)Praw + e * 64 + q * 16);
        pk.u[1] = *(const uint4*)((const __hip_bfloat16*)Praw + e * 64 + q * 16 + 8);
    } else {
        const float* ps = (const float*)Praw + e * 64 + q * 16;
#pragma unroll
        for (int j = 0; j < 16; ++j) pk.h[j] = __float2bfloat16(ps[j]);
    }
    *(uint4*)&sP[e * 72 + q * 16]     = pk.u[0];
    *(uint4*)&sP[e * 72 + q * 16 + 8] = pk.u[1];
}

__device__ __forceinline__ float sumsq16(uint4 a, uint4 b) {
    union { uint4 u; __hip_bfloat16 h[8]; } x0, x1;
    x0.u = a; x1.u = b;
    float ss = 0.f;
#pragma unroll
    for (int j = 0; j < 8; ++j) {
        float v0 = __bfloat162float(x0.h[j]); ss += v0 * v0;
        float v1 = __bfloat162float(x1.h[j]); ss += v1 * v1;
    }
    return ss;
}

// ----------------------------- kv kernel -----------------------------------
// grid (8, 64): 512 tokens per block, 8 iters. Partial kv -> private slab
// (plain stores, no atomics). Slab layout: PKV[(slab*64 + bh)*8192 + e*64+d].
__global__ __launch_bounds__(256) void kv_kernel(
    const __hip_bfloat16* __restrict__ Km,
    const __hip_bfloat16* __restrict__ Vm,
    const void* __restrict__ Praw,
    float* __restrict__ PKV,
    const int* __restrict__ flag)
{
    __shared__ __hip_bfloat16 sK[64 * 72];     // [n][d] (wave-local rows)
    __shared__ __hip_bfloat16 sVT[64 * 72];    // [d][n] (cross-wave)
    __shared__ __hip_bfloat16 sP[64 * 72];     // [e][d] (read-only)
    __shared__ __hip_bfloat16 sKFT[128 * 72];  // [e][n] (cross-wave)
    __shared__ float sRN[64];

    const int tid  = threadIdx.x;
    const int lane = tid & 63;
    const int w    = tid >> 6;
    const int lr   = lane & 15, lk = lane >> 4;
    const int bh   = blockIdx.y;
    const int b    = bh >> 4, h = bh & 15;
    const int nst  = blockIdx.x * 512;
    const int f    = *flag;
    const int n    = tid >> 2, q2 = tid & 3;

    load_P(Praw, f, sP, tid);

    f32x4 acck[2][4];
#pragma unroll
    for (int i = 0; i < 2; ++i)
#pragma unroll
        for (int j = 0; j < 4; ++j)
            acck[i][j] = (f32x4){0.f, 0.f, 0.f, 0.f};

    size_t base = ((size_t)(b * 4096 + nst + n)) * 1024 + h * 64 + q2 * 16;
    uint4 ka = *(const uint4*)(Km + base), kb = *(const uint4*)(Km + base + 8);
    uint4 va = *(const uint4*)(Vm + base), vb = *(const uint4*)(Vm + base + 8);

    for (int s = 0; s < 8; ++s) {
        __syncthreads();  // prev kv-MFMA done with sVT/sKFT (s==0: sP visible)
        *(uint4*)&sK[n * 72 + q2 * 16]     = ka;
        *(uint4*)&sK[n * 72 + q2 * 16 + 8] = kb;
        {
            union { uint4 u[2]; __hip_bfloat16 h[16]; } vv;
            vv.u[0] = va; vv.u[1] = vb;
#pragma unroll
            for (int j = 0; j < 16; ++j) sVT[(q2 * 16 + j) * 72 + n] = vv.h[j];
        }
        {
            float ss = sumsq16(ka, kb);
            ss += __shfl_xor(ss, 1, 64);
            ss += __shfl_xor(ss, 2, 64);
            if (q2 == 0) sRN[n] = 2.0f / (sqrtf(ss) + 1e-4f);  // H^0.25 = 2
        }
        if (s < 7) {
            base = ((size_t)(b * 4096 + nst + (s + 1) * 64 + n)) * 1024 + h * 64 + q2 * 16;
            ka = *(const uint4*)(Km + base); kb = *(const uint4*)(Km + base + 8);
            va = *(const uint4*)(Vm + base); vb = *(const uint4*)(Vm + base + 8);
        }
        // proj (wave-local) + sincos -> sKFT
        {
            bf16x8 afr0 = *(const bf16x8*)&sK[(w * 16 + lr) * 72 + lk * 8];
            bf16x8 afr1 = *(const bf16x8*)&sK[(w * 16 + lr) * 72 + 32 + lk * 8];
            float rn[4];
#pragma unroll
            for (int r = 0; r < 4; ++r) rn[r] = sRN[w * 16 + lk * 4 + r];
#pragma unroll
            for (int eb = 0; eb < 4; ++eb) {
                f32x4 pa = (f32x4){0.f, 0.f, 0.f, 0.f};
                bf16x8 b0 = *(const bf16x8*)&sP[(eb * 16 + lr) * 72 + lk * 8];
                bf16x8 b1 = *(const bf16x8*)&sP[(eb * 16 + lr) * 72 + 32 + lk * 8];
                pa = __builtin_amdgcn_mfma_f32_16x16x32_bf16(afr0, b0, pa, 0, 0, 0);
                pa = __builtin_amdgcn_mfma_f32_16x16x32_bf16(afr1, b1, pa, 0, 0, 0);
                const int col = eb * 16 + lr;
#pragma unroll
                for (int r = 0; r < 4; ++r) {
                    const int row = w * 16 + lk * 4 + r;
                    float sv, cv;
                    __sincosf(pa[r] * rn[r], &sv, &cv);
                    sKFT[col * 72 + row]        = __float2bfloat16(sv * 0.125f);
                    sKFT[(col + 64) * 72 + row] = __float2bfloat16(cv * 0.125f);
                }
            }
        }
        __syncthreads();  // sKFT + sVT complete across waves
#pragma unroll
        for (int ks = 0; ks < 2; ++ks) {
            bf16x8 a2[2], b2[4];
            a2[0] = *(const bf16x8*)&sKFT[(w * 16 + lr) * 72 + ks * 32 + lk * 8];
            a2[1] = *(const bf16x8*)&sKFT[((w + 4) * 16 + lr) * 72 + ks * 32 + lk * 8];
#pragma unroll
            for (int db = 0; db < 4; ++db)
                b2[db] = *(const bf16x8*)&sVT[(db * 16 + lr) * 72 + ks * 32 + lk * 8];
#pragma unroll
            for (int i = 0; i < 2; ++i)
#pragma unroll
                for (int db = 0; db < 4; ++db)
                    acck[i][db] = __builtin_amdgcn_mfma_f32_16x16x32_bf16(
                        a2[i], b2[db], acck[i][db], 0, 0, 0);
        }
    }

    float* out = PKV + ((size_t)blockIdx.x * 64 + bh) * 8192;
#pragma unroll
    for (int i = 0; i < 2; ++i)
#pragma unroll
        for (int db = 0; db < 4; ++db)
#pragma unroll
            for (int r = 0; r < 4; ++r) {
                const int e = (w + 4 * i) * 16 + lk * 4 + r;
                const int d = db * 16 + lr;
                out[e * 64 + d] = acck[i][db][r];
            }
}

// --------------------------- kv reduce kernel ------------------------------
// gKV[i] = sum over 8 slabs of PKV. 512 blocks x 256 thr x float4.
__global__ __launch_bounds__(256) void kv_reduce_kernel(
    const float* __restrict__ PKV, float* __restrict__ gKV)
{
    const int i = (blockIdx.x * 256 + threadIdx.x) * 4;
    f32x4 s = (f32x4){0.f, 0.f, 0.f, 0.f};
#pragma unroll
    for (int sl = 0; sl < KV_SLABS; ++sl) {
        const float4 v = *(const float4*)(PKV + (size_t)sl * 64 * 8192 + i);
        s[0] += v.x; s[1] += v.y; s[2] += v.z; s[3] += v.w;
    }
    *(float4*)(gKV + i) = *(float4*)&s;
}

// ----------------------------- o kernel ------------------------------------
__global__ __launch_bounds__(256) void o_kernel(
    const __hip_bfloat16* __restrict__ Qm,
    const void* __restrict__ Praw,
    const float* __restrict__ gKV,
    __hip_bfloat16* __restrict__ O,
    const int* __restrict__ flag)
{
    __shared__ __hip_bfloat16 sQ[64 * 72];     // [n][d] wave-local rows
    __shared__ __hip_bfloat16 sP[64 * 72];     // read-only
    __shared__ __hip_bfloat16 sQF[64 * 136];   // [n][e] wave-local rows
    __shared__ __hip_bfloat16 sKVT[64 * 136];  // [d][e] read-only
    __shared__ float sRN[64];

    const int tid  = threadIdx.x;
    const int lane = tid & 63;
    const int w    = tid >> 6;
    const int lr   = lane & 15, lk = lane >> 4;
    const int bh   = blockIdx.y;
    const int b    = bh >> 4, h = bh & 15;
    const int nst  = blockIdx.x * 256;
    const int f    = *flag;
    const int n    = tid >> 2, q2 = tid & 3;

    load_P(Praw, f, sP, tid);
    {
        const float* kvsrc = gKV + (size_t)bh * 8192;
        for (int t = tid; t < 8192; t += 256) {
            const int e = t >> 6, d = t & 63;
            sKVT[d * 136 + e] = __float2bfloat16(kvsrc[t]);
        }
    }

    size_t base = ((size_t)(b * 4096 + nst + n)) * 1024 + h * 64 + q2 * 16;
    uint4 qa = *(const uint4*)(Qm + base), qb = *(const uint4*)(Qm + base + 8);

    __syncthreads();  // sP + sKVT visible to all waves

    for (int s = 0; s < 4; ++s) {
        const int gn0 = nst + s * 64;
        *(uint4*)&sQ[n * 72 + q2 * 16]     = qa;
        *(uint4*)&sQ[n * 72 + q2 * 16 + 8] = qb;
        {
            float ss = sumsq16(qa, qb);
            ss += __shfl_xor(ss, 1, 64);
            ss += __shfl_xor(ss, 2, 64);
            if (q2 == 0) sRN[n] = 2.0f / (sqrtf(ss) + 1e-4f);
        }
        if (s < 3) {
            base = ((size_t)(b * 4096 + nst + (s + 1) * 64 + n)) * 1024 + h * 64 + q2 * 16;
            qa = *(const uint4*)(Qm + base); qb = *(const uint4*)(Qm + base + 8);
        }
        {
            bf16x8 afr0 = *(const bf16x8*)&sQ[(w * 16 + lr) * 72 + lk * 8];
            bf16x8 afr1 = *(const bf16x8*)&sQ[(w * 16 + lr) * 72 + 32 + lk * 8];
            float rn[4];
#pragma unroll
            for (int r = 0; r < 4; ++r) rn[r] = sRN[w * 16 + lk * 4 + r];
#pragma unroll
            for (int eb = 0; eb < 4; ++eb) {
                f32x4 pa = (f32x4){0.f, 0.f, 0.f, 0.f};
                bf16x8 b0 = *(const bf16x8*)&sP[(eb * 16 + lr) * 72 + lk * 8];
                bf16x8 b1 = *(const bf16x8*)&sP[(eb * 16 + lr) * 72 + 32 + lk * 8];
                pa = __builtin_amdgcn_mfma_f32_16x16x32_bf16(afr0, b0, pa, 0, 0, 0);
                pa = __builtin_amdgcn_mfma_f32_16x16x32_bf16(afr1, b1, pa, 0, 0, 0);
                const int col = eb * 16 + lr;
#pragma unroll
                for (int r = 0; r < 4; ++r) {
                    const int row = w * 16 + lk * 4 + r;
                    float sv, cv;
                    __sincosf(pa[r] * rn[r], &sv, &cv);
                    sQF[row * 136 + col]      = __float2bfloat16(sv * 0.125f);
                    sQF[row * 136 + 64 + col] = __float2bfloat16(cv * 0.125f);
                }
            }
        }
        f32x4 oacc[4];
#pragma unroll
        for (int nb = 0; nb < 4; ++nb) oacc[nb] = (f32x4){0.f, 0.f, 0.f, 0.f};
#pragma unroll
        for (int ks = 0; ks < 4; ++ks) {
            bf16x8 aa = *(const bf16x8*)&sQF[(w * 16 + lr) * 136 + ks * 32 + lk * 8];
#pragma unroll
            for (int nb = 0; nb < 4; ++nb) {
                bf16x8 bb = *(const bf16x8*)&sKVT[(nb * 16 + lr) * 136 + ks * 32 + lk * 8];
                oacc[nb] = __builtin_amdgcn_mfma_f32_16x16x32_bf16(aa, bb, oacc[nb], 0, 0, 0);
            }
        }
#pragma unroll
        for (int nb = 0; nb < 4; ++nb)
#pragma unroll
            for (int r = 0; r < 4; ++r)
                sQ[(w * 16 + lk * 4 + r) * 72 + nb * 16 + lr] =
                    __float2bfloat16(oacc[nb][r]);
        {
            uint4 o0 = *(uint4*)&sQ[n * 72 + q2 * 16];
            uint4 o1 = *(uint4*)&sQ[n * 72 + q2 * 16 + 8];
            const size_t obase = ((size_t)(b * 4096 + gn0 + n)) * 1024 + h * 64 + q2 * 16;
            *(uint4*)(O + obase)     = o0;
            *(uint4*)(O + obase + 8) = o1;
        }
    }
}

// ----------------------------- launcher ------------------------------------
extern "C" void kernel_launch(void* const* d_in, const int* in_sizes, int n_in,
                              void* d_out, int out_size, void* d_ws, size_t ws_size,
                              hipStream_t stream)
{
    (void)in_sizes; (void)n_in; (void)out_size; (void)ws_size;
    const void* x  = d_in[0];
    const void* Wq = d_in[1];
    const void* bq = d_in[2];
    const void* Wk = d_in[3];
    const void* bk = d_in[4];
    const void* Wv = d_in[5];
    const void* bv = d_in[6];
    const void* Wo = d_in[7];
    const void* bo = d_in[8];
    const void* P  = d_in[9];

    constexpr size_t XE = (size_t)GM * GN;
    constexpr size_t WE = (size_t)GN * GK;
    constexpr size_t KVE = (size_t)64 * 128 * 64;

    __hip_bfloat16* xb  = (__hip_bfloat16*)d_ws;
    __hip_bfloat16* wqb = xb + XE;
    __hip_bfloat16* wkb = wqb + WE;
    __hip_bfloat16* wvb = wkb + WE;
    __hip_bfloat16* wob = wvb + WE;
    __hip_bfloat16* R1  = wob + WE;          // K, later O
    __hip_bfloat16* R2  = R1 + XE;           // V, later Q
    float* gKV = (float*)(R2 + XE);
    float* PKV = gKV + KVE;                  // 8 slabs x 64 x 8192
    int* flag  = (int*)(PKV + (size_t)KV_SLABS * 64 * 8192);

    dim3 blk(256);
    hipLaunchKernelGGL(detect_kernel, dim3(1), dim3(64), 0, stream,
                       (const unsigned short*)x, flag);

    hipLaunchKernelGGL(cvt_kernel, dim3(8192), blk, 0, stream, x,  xb,  (int)XE, flag);
    hipLaunchKernelGGL(cvt_kernel, dim3(512),  blk, 0, stream, Wq, wqb, (int)WE, flag);
    hipLaunchKernelGGL(cvt_kernel, dim3(512),  blk, 0, stream, Wk, wkb, (int)WE, flag);
    hipLaunchKernelGGL(cvt_kernel, dim3(512),  blk, 0, stream, Wv, wvb, (int)WE, flag);
    hipLaunchKernelGGL(cvt_kernel, dim3(512),  blk, 0, stream, Wo, wob, (int)WE, flag);

    // K,V (2-out, shared A)
    hipLaunchKernelGGL(gemm2_kernel, dim3(1024), blk, 0, stream,
                       x, xb, Wk, wkb, Wv, wvb, bk, bv, R1, R2, flag);
    hipLaunchKernelGGL(kv_kernel, dim3(KV_SLABS, 64), blk, 0, stream, R1, R2, P, PKV, flag);
    hipLaunchKernelGGL(kv_reduce_kernel, dim3(512), blk, 0, stream, PKV, gKV);
    // Q (V dead -> R2), dual-M
    hipLaunchKernelGGL(gemm1m2_kernel, dim3(512), blk, 0, stream,
                       x, xb, Wq, wqb, bq, R2, flag, 0);
    hipLaunchKernelGGL(o_kernel, dim3(16, 64), blk, 0, stream, R2, P, gKV, R1, flag);
    // out = O@Wo^T + bo, dual-M
    hipLaunchKernelGGL(gemm1m2_kernel, dim3(512), blk, 0, stream,
                       R1, R1, Wo, wob, bo, d_out, flag, 1);
}